// Round 11
// baseline (720.563 us; speedup 1.0000x reference)
//
#include <hip/hip_runtime.h>
#include <hip/hip_bf16.h>

#define N_NODE 100000
#define N_USER 40000
#define N_PRICE 100
#define EMB 128
#define E_VV 2000000
#define E_VP 200000
#define E_VU 2000000
#define E_UV 2000000

#define FOFF0 0
#define FOFF1 256
#define FOFF2 512
#define FOFF3 767
#define FOFF4 1023
#define FTOT  1073
#define EPB   8192
#define BK1 245
#define BK2 490
#define BK3 735
#define BK4 760
#define BKT 785
#define CB1 256
#define CB2 512
#define CB3 767
#define CB4 1023
#define CBT 1073
#define RB_PV   100
#define RB_ITEM 25000
#define RB_USER 10000
#define RBT (RB_PV + RB_ITEM + RB_USER)
#define FB_ITEM 782
#define FB_USER 313
#define FBT (FB_ITEM + FB_USER + 50)

#define CAPA 12032   // padded capacity, big lists (multiple of 16)
#define MARK 0xFFFFFFFFu

typedef __attribute__((ext_vector_type(8))) short short8;
typedef __attribute__((ext_vector_type(4))) float f32x4;

__device__ __forceinline__ float sigf(float x){ return 1.f/(1.f+__expf(-x)); }
__device__ __forceinline__ unsigned bfr(float f){
  unsigned u = __float_as_uint(f);
  return (u + 0x7FFFu + ((u>>16)&1u)) >> 16;
}
__device__ __forceinline__ float bf_lo(unsigned u){ return __uint_as_float(u << 16); }
__device__ __forceinline__ float bf_hi(unsigned u){ return __uint_as_float(u & 0xFFFF0000u); }
__device__ __forceinline__ unsigned pack2(float x, float y){ return bfr(x) | (bfr(y)<<16); }

// ---------------- fused f32 -> packed bf16 convert (all 3 tables) ----------------
__global__ __launch_bounds__(256) void k_cvt_all(
    const float4* __restrict__ se, const float4* __restrict__ su, const float4* __restrict__ sp,
    uint2* __restrict__ de, uint2* __restrict__ du, uint2* __restrict__ dp){
  const int nE = N_NODE*EMB/4, nU = N_USER*EMB/4, nP = N_PRICE*EMB/4;
  int i = blockIdx.x*256 + threadIdx.x;
  const float4* src; uint2* dst; int j;
  if (i < nE){ src = se; dst = de; j = i; }
  else if (i < nE+nU){ src = su; dst = du; j = i-nE; }
  else if (i < nE+nU+nP){ src = sp; dst = dp; j = i-nE-nU; }
  else return;
  float4 v = src[j];
  dst[j] = make_uint2(bfr(v.x) | (bfr(v.y)<<16), bfr(v.z) | (bfr(v.w)<<16));
}

// ---------------- prep: bf16 weights + zero fills + zero sentinels ----------------
__global__ __launch_bounds__(256) void k_prep(
    const float* __restrict__ Wa, const float* __restrict__ Wb, const float* __restrict__ Wu,
    ushort* __restrict__ Wc, ushort* __restrict__ Wub,
    int* __restrict__ fill,
    int2* __restrict__ adjE, int2* __restrict__ vuE, int2* __restrict__ uvE,
    int2* __restrict__ vpE, int2* __restrict__ pvE){
  if (blockIdx.x == 320){
    int t = threadIdx.x;
    for (int i = t; i < 2*FTOT; i += 256) fill[i] = 0;
    if (t < 16){
      int2 z = make_int2(0,0);
      adjE[E_VV+t] = z; vuE[E_VU+t] = z; uvE[E_UV+t] = z; vpE[E_VP+t] = z; pvE[E_VP+t] = z;
    }
    return;
  }
  int idx = blockIdx.x*256 + threadIdx.x;
  if (idx < 128*256){
    int n = idx >> 8, k = idx & 255;
    float v = Wa[n*256+k] + ((k < 128) ? Wb[n*128+k] : 0.f);
    Wc[idx] = (ushort)bfr(v);
  } else {
    int j = idx - 128*256;
    if (j < 128*384) Wub[j] = (ushort)bfr(Wu[j]);
  }
}

// ---------------- Pass A: bucket edges, 128B-aligned chunk reservations ----------------
template<int E, int RPB, int NB, int CAPc>
__device__ __forceinline__ void bucket_body(int blk,
    const int* __restrict__ rows, const int* __restrict__ cols, const float* __restrict__ vals,
    int* __restrict__ fillPad, int* __restrict__ fillReal,
    uint2* __restrict__ stg, int* cnt, int* gbase)
{
  const int t = threadIdx.x;
  const int e0 = blk * EPB;
  for (int i = t; i < NB; i += 256) cnt[i] = 0;
  __syncthreads();
  int rr[32];
  #pragma unroll
  for (int i = 0; i < 32; ++i){
    int e = e0 + i*256 + t;
    rr[i] = (e < E) ? rows[e] : -1;
    if (rr[i] >= 0) atomicAdd(&cnt[rr[i]/RPB], 1);
  }
  __syncthreads();
  for (int b = t; b < NB; b += 256){
    int c = cnt[b];
    int gb = 0;
    if (c > 0){
      int rounded = (c + 15) & ~15;
      gb = atomicAdd(&fillPad[b], rounded);
      atomicAdd(&fillReal[b], c);
      for (int j = c; j < rounded; ++j){        // marker pads -> full-line chunks
        int slot = gb + j; if (slot >= CAPc) slot = CAPc - 1;
        stg[(size_t)b*CAPc + slot] = make_uint2(MARK, 0u);
      }
    }
    gbase[b] = gb;
    cnt[b] = 0;
  }
  __syncthreads();
  #pragma unroll
  for (int i = 0; i < 32; ++i){
    if (rr[i] >= 0){
      int e = e0 + i*256 + t;
      int b = rr[i]/RPB, rl = rr[i] - b*RPB;
      int slot = gbase[b] + atomicAdd(&cnt[b], 1);
      if (slot >= CAPc) slot = CAPc - 1;
      stg[(size_t)b*CAPc + slot] = make_uint2((unsigned)cols[e] | ((unsigned)rl << 17), __float_as_uint(vals[e]));
    }
  }
}

__global__ __launch_bounds__(256) void k_bucket_all(
    const int* __restrict__ aR, const int* __restrict__ aC, const float* __restrict__ aV,
    const int* __restrict__ uR, const int* __restrict__ uC, const float* __restrict__ uV,
    const int* __restrict__ vR, const int* __restrict__ vC, const float* __restrict__ vV,
    const int* __restrict__ pR, const int* __restrict__ pC, const float* __restrict__ pV,
    const int* __restrict__ qR, const int* __restrict__ qC, const float* __restrict__ qV,
    int* __restrict__ fillPad, int* __restrict__ fillReal,
    uint2* __restrict__ stgA, uint2* __restrict__ stgU, uint2* __restrict__ stgV,
    uint2* __restrict__ stgP, uint2* __restrict__ stgQ)
{
  __shared__ int cnt[256], gbase[256];
  int b = blockIdx.x;
  if      (b < BK1) bucket_body<E_VV,391,256,CAPA>(b,      aR,aC,aV, fillPad+FOFF0, fillReal+FOFF0, stgA, cnt, gbase);
  else if (b < BK2) bucket_body<E_VU,391,256,CAPA>(b-BK1,  uR,uC,uV, fillPad+FOFF1, fillReal+FOFF1, stgU, cnt, gbase);
  else if (b < BK3) bucket_body<E_UV,157,255,CAPA>(b-BK2,  vR,vC,vV, fillPad+FOFF2, fillReal+FOFF2, stgV, cnt, gbase);
  else if (b < BK4) bucket_body<E_VP,391,256,1536>(b-BK3,  pR,pC,pV, fillPad+FOFF3, fillReal+FOFF3, stgP, cnt, gbase);
  else              bucket_body<E_VP,  2, 50,5632>(b-BK4,  qR,qC,qV, fillPad+FOFF4, fillReal+FOFF4, stgQ, cnt, gbase);
}

// ---------------- Pass B: CSR finalize, 16-bin column grouping, compact coalesced flush ----------------
template<int NROW, int RPB, int NB, int CAPc, int BINS>
__device__ __forceinline__ void csr_body(int b,
    const uint2* __restrict__ stg, const int* __restrict__ fillPad, const int* __restrict__ fillReal,
    int* __restrict__ start, int2* __restrict__ csr,
    int* cnt2, uint2* stage, int* sbase, int* stot)
{
  const int t = threadIdx.x;
  const int row0 = b * RPB;
  int R = NROW - row0; if (R > RPB) R = RPB;
  int cpad = fillPad[b]; if (cpad > CAPc) cpad = CAPc;
  for (int i = t; i < BINS; i += 256) cnt2[i] = 0;
  if (t < 64){   // exclusive prefix of fillReal[0..NB) at index b -> compact global base
    int run = 0;
    for (int c0 = 0; c0 < NB; c0 += 64){
      int j = c0 + t;
      int x = (j < NB) ? fillReal[j] : 0;
      int s = x;
      #pragma unroll
      for (int d = 1; d < 64; d <<= 1){ int y = __shfl_up(s, d); if (t >= d) s += y; }
      if (j == b) *sbase = run + s - x;
      run += __shfl(s, 63);
    }
  }
  __syncthreads();
  const int base = *sbase;
  const uint2* mystg = stg + (size_t)b*CAPc;
  for (int j = t; j < cpad; j += 256){
    unsigned x = mystg[j].x;
    if (x != MARK)
      atomicAdd(&cnt2[((x >> 17) << 4) | ((x & 0x1FFFFu) >> 13)], 1);
  }
  __syncthreads();
  if (t < 64){   // exclusive scan of cnt2[0..BINS)
    int run = 0;
    for (int c0 = 0; c0 < BINS; c0 += 64){
      int i = c0 + t;
      int x = (i < BINS) ? cnt2[i] : 0;
      int s = x;
      #pragma unroll
      for (int d = 1; d < 64; d <<= 1){ int y = __shfl_up(s, d); if (t >= d) s += y; }
      if (i < BINS) cnt2[i] = run + s - x;
      run += __shfl(s, 63);
    }
    if (t == 0) *stot = run;
  }
  __syncthreads();
  const int creal = *stot;
  for (int i = t; i < R; i += 256) start[row0 + i] = base + cnt2[i*16];
  if (b == NB-1 && t == 0) start[NROW] = base + creal;
  __syncthreads();
  for (int j = t; j < cpad; j += 256){   // group into LDS by (row, col-hi), skip markers
    uint2 kv = mystg[j];
    if (kv.x != MARK){
      int key = ((kv.x >> 17) << 4) | ((kv.x & 0x1FFFFu) >> 13);
      int pos = atomicAdd(&cnt2[key], 1);
      stage[pos] = kv;
    }
  }
  __syncthreads();
  for (int j = t; j < creal; j += 256){  // compact coalesced flush, strip rl bits
    uint2 kv = stage[j];
    csr[base + j] = make_int2((int)(kv.x & 0x1FFFF), (int)kv.y);
  }
}

__global__ __launch_bounds__(256) void k_csr_all(
    const uint2* __restrict__ stgA, const uint2* __restrict__ stgU, const uint2* __restrict__ stgV,
    const uint2* __restrict__ stgP, const uint2* __restrict__ stgQ,
    const int* __restrict__ fillPad, const int* __restrict__ fillReal,
    int* __restrict__ aS, int* __restrict__ uS, int* __restrict__ vS,
    int* __restrict__ pS, int* __restrict__ qS,
    int2* __restrict__ aE, int2* __restrict__ uE, int2* __restrict__ vE,
    int2* __restrict__ pE, int2* __restrict__ qE)
{
  __shared__ int cnt2[6256];
  __shared__ int sbase, stot;
  __shared__ uint2 stage[8704];
  int b = blockIdx.x;
  if      (b < CB1) csr_body<N_NODE,391,256,CAPA,6256>(b,     stgA, fillPad+FOFF0, fillReal+FOFF0, aS, aE, cnt2, stage, &sbase, &stot);
  else if (b < CB2) csr_body<N_NODE,391,256,CAPA,6256>(b-CB1, stgU, fillPad+FOFF1, fillReal+FOFF1, uS, uE, cnt2, stage, &sbase, &stot);
  else if (b < CB3) csr_body<N_USER,157,255,CAPA,2512>(b-CB2, stgV, fillPad+FOFF2, fillReal+FOFF2, vS, vE, cnt2, stage, &sbase, &stot);
  else if (b < CB4) csr_body<N_NODE,391,256,1536,6256>(b-CB3, stgP, fillPad+FOFF3, fillReal+FOFF3, pS, pE, cnt2, stage, &sbase, &stot);
  else              csr_body<N_PRICE,  2, 50,5632,  32>(b-CB4, stgQ, fillPad+FOFF4, fillReal+FOFF4, qS, qE, cnt2, stage, &sbase, &stot);
}

// ======== row SpMMs: 16 lanes/edge, uint4 gathers (unchanged from R10) ========

#define FMA8(ACC, U, V)                                     \
  ACC[0] += (V)*bf_lo((U).x); ACC[1] += (V)*bf_hi((U).x);   \
  ACC[2] += (V)*bf_lo((U).y); ACC[3] += (V)*bf_hi((U).y);   \
  ACC[4] += (V)*bf_lo((U).z); ACC[5] += (V)*bf_hi((U).z);   \
  ACC[6] += (V)*bf_lo((U).w); ACC[7] += (V)*bf_hi((U).w);

#define RED8(ACC)                                           \
  _Pragma("unroll")                                         \
  for (int j = 0; j < 8; ++j){                              \
    ACC[j] += __shfl_xor(ACC[j], 16);                       \
    ACC[j] += __shfl_xor(ACC[j], 32);                       \
  }

__device__ __forceinline__ void item_body(int rb,
    const uint4* __restrict__ be4, const uint4* __restrict__ bu4, const uint4* __restrict__ bp4,
    const int* __restrict__ aS, const int2* __restrict__ aE,
    const int* __restrict__ uS, const int2* __restrict__ uE,
    const int* __restrict__ pS, const int2* __restrict__ pE,
    const float* __restrict__ mat_vu, const float* __restrict__ lam,
    float4* __restrict__ out4, uint4* __restrict__ vp4)
{
  const int r = rb*4 + (threadIdx.x >> 6);
  const int l = threadIdx.x & 63;
  const int g = l >> 4, q = l & 15;
  float aA[8] = {}, aU[8] = {}, aP[8] = {};
  float den = 0.f;
  int s = aS[r], e = aS[r+1];
  for (int i = s; i < e; i += 16){
    int2 cv[4]; uint4 u[4];
    #pragma unroll
    for (int k = 0; k < 4; ++k) cv[k] = aE[i + 4*k + g];
    #pragma unroll
    for (int k = 0; k < 4; ++k) u[k] = be4[(size_t)cv[k].x*16 + q];
    #pragma unroll
    for (int k = 0; k < 4; ++k){
      float v = (i + 4*k + g < e) ? __int_as_float(cv[k].y) : 0.f;
      FMA8(aA, u[k], v)
    }
  }
  s = uS[r]; e = uS[r+1];
  for (int i = s; i < e; i += 16){
    int2 cv[4]; uint4 u[4];
    #pragma unroll
    for (int k = 0; k < 4; ++k) cv[k] = uE[i + 4*k + g];
    #pragma unroll
    for (int k = 0; k < 4; ++k) u[k] = bu4[(size_t)cv[k].x*16 + q];
    #pragma unroll
    for (int k = 0; k < 4; ++k){
      float v = (i + 4*k + g < e) ? __int_as_float(cv[k].y) : 0.f;
      FMA8(aU, u[k], v)
      den += v;
    }
  }
  s = pS[r]; e = pS[r+1];
  for (int i = s; i < e; i += 16){
    int2 cv[4]; uint4 u[4];
    #pragma unroll
    for (int k = 0; k < 4; ++k) cv[k] = pE[i + 4*k + g];
    #pragma unroll
    for (int k = 0; k < 4; ++k) u[k] = bp4[(size_t)cv[k].x*16 + q];
    #pragma unroll
    for (int k = 0; k < 4; ++k){
      float v = (i + 4*k + g < e) ? __int_as_float(cv[k].y) : 0.f;
      FMA8(aP, u[k], v)
    }
  }
  RED8(aA) RED8(aU) RED8(aP)
  den += __shfl_xor(den, 16); den += __shfl_xor(den, 32);
  float sc = lam[0]*mat_vu[r]/(den + 1e-8f);
  if (g == 0){
    out4[(size_t)r*32 + q*2]     = make_float4(aA[0]+sc*aU[0], aA[1]+sc*aU[1], aA[2]+sc*aU[2], aA[3]+sc*aU[3]);
    out4[(size_t)r*32 + q*2 + 1] = make_float4(aA[4]+sc*aU[4], aA[5]+sc*aU[5], aA[6]+sc*aU[6], aA[7]+sc*aU[7]);
    vp4[(size_t)r*16 + q] = make_uint4(pack2(aP[0],aP[1]), pack2(aP[2],aP[3]), pack2(aP[4],aP[5]), pack2(aP[6],aP[7]));
  }
}

__device__ __forceinline__ void user_body(int rb,
    const uint4* __restrict__ be4, const uint4* __restrict__ bp4,
    const int* __restrict__ S, const int2* __restrict__ E,
    const int* __restrict__ ipi, const float* __restrict__ mat_uv,
    uint4* __restrict__ eit4, uint4* __restrict__ uvp4)
{
  const int r = rb*4 + (threadIdx.x >> 6);
  const int l = threadIdx.x & 63;
  const int g = l >> 4, q = l & 15;
  float aI[8] = {}, aP[8] = {};
  float den = 0.f;
  int s = S[r], e = S[r+1];
  for (int i = s; i < e; i += 8){
    int2 cv[2];
    #pragma unroll
    for (int k = 0; k < 2; ++k) cv[k] = E[i + 4*k + g];
    uint4 u[2]; int ip[2];
    #pragma unroll
    for (int k = 0; k < 2; ++k){ u[k] = be4[(size_t)cv[k].x*16 + q]; ip[k] = ipi[cv[k].x]; }
    uint4 y[2];
    #pragma unroll
    for (int k = 0; k < 2; ++k) y[k] = bp4[(size_t)ip[k]*16 + q];
    #pragma unroll
    for (int k = 0; k < 2; ++k){
      float v = (i + 4*k + g < e) ? __int_as_float(cv[k].y) : 0.f;
      FMA8(aI, u[k], v)
      FMA8(aP, y[k], v)
      den += v;
    }
  }
  RED8(aI) RED8(aP)
  den += __shfl_xor(den, 16); den += __shfl_xor(den, 32);
  float sc = mat_uv[r]/(den + 1e-8f);
  if (g == 0){
    eit4[(size_t)r*16 + q] = make_uint4(pack2(sc*aI[0],sc*aI[1]), pack2(sc*aI[2],sc*aI[3]),
                                        pack2(sc*aI[4],sc*aI[5]), pack2(sc*aI[6],sc*aI[7]));
    uvp4[(size_t)r*16 + q] = make_uint4(pack2(aP[0],aP[1]), pack2(aP[2],aP[3]),
                                        pack2(aP[4],aP[5]), pack2(aP[6],aP[7]));
  }
}

__device__ __forceinline__ void pv_body(int r,
    const uint4* __restrict__ be4, const int2* __restrict__ E, const int* __restrict__ S,
    float* __restrict__ num, float* __restrict__ den_out)
{
  const int t = threadIdx.x;
  const int wid = t >> 6, l = t & 63;
  const int g = l >> 4, q = l & 15;
  float aP[8] = {}; float den = 0.f;
  int s = S[r], e = S[r+1];
  for (int i0 = s + wid*16; i0 < e; i0 += 64){
    int2 cv[4]; uint4 u[4];
    #pragma unroll
    for (int k = 0; k < 4; ++k) cv[k] = E[i0 + 4*k + g];
    #pragma unroll
    for (int k = 0; k < 4; ++k) u[k] = be4[(size_t)cv[k].x*16 + q];
    #pragma unroll
    for (int k = 0; k < 4; ++k){
      float v = (i0 + 4*k + g < e) ? __int_as_float(cv[k].y) : 0.f;
      FMA8(aP, u[k], v)
      den += v;
    }
  }
  RED8(aP)
  den += __shfl_xor(den, 16); den += __shfl_xor(den, 32);
  __shared__ float red[4][16][8];
  __shared__ float dred[4];
  if (g == 0){
    #pragma unroll
    for (int j = 0; j < 8; ++j) red[wid][q][j] = aP[j];
    if (l == 0) dred[wid] = den;
  }
  __syncthreads();
  if (t < 16){
    #pragma unroll
    for (int j = 0; j < 8; ++j)
      num[r*128 + t*8 + j] = red[0][t][j] + red[1][t][j] + red[2][t][j] + red[3][t][j];
    if (t == 0) den_out[r] = dred[0] + dred[1] + dred[2] + dred[3];
  }
}

__global__ __launch_bounds__(256) void k_rows_all(
    const uint4* __restrict__ be4, const uint4* __restrict__ bu4, const uint4* __restrict__ bp4,
    const int* __restrict__ aS, const int2* __restrict__ aE,
    const int* __restrict__ uS, const int2* __restrict__ uE,
    const int* __restrict__ pS, const int2* __restrict__ pE,
    const int* __restrict__ vS, const int2* __restrict__ vE,
    const int* __restrict__ qS, const int2* __restrict__ qE,
    const int* __restrict__ ipi,
    const float* __restrict__ mat_vu, const float* __restrict__ mat_uv, const float* __restrict__ lam,
    float4* __restrict__ out4, uint4* __restrict__ vp4,
    uint4* __restrict__ eit4, uint4* __restrict__ uvp4,
    float* __restrict__ pv_num, float* __restrict__ pv_den)
{
  int b = blockIdx.x;
  if (b < RB_PV){ pv_body(b, be4, qE, qS, pv_num, pv_den); return; }
  b -= RB_PV;
  if (b < RB_ITEM){ item_body(b, be4, bu4, bp4, aS, aE, uS, uE, pS, pE, mat_vu, lam, out4, vp4); return; }
  b -= RB_ITEM;
  user_body(b, be4, bp4, vS, vE, ipi, mat_uv, eit4, uvp4);
}

// ======== finals (unchanged from R10) ========
__device__ __forceinline__ void item_final_body(int blk, ushort* As, ushort* Bs,
    const ushort* __restrict__ A0, const ushort* __restrict__ A1,
    const ushort* __restrict__ W,
    const float* __restrict__ ba, const float* __restrict__ bb,
    const float* __restrict__ emb, float* __restrict__ out)
{
  const int t = threadIdx.x;
  const int l = t & 63, wv = t >> 6;
  const int wr = (wv>>1)*64, wc = (wv&1)*64;
  const int row0 = blk*128;
  const int lr16 = t >> 3;
  const int slot = t & 7;
  f32x4 acc[4][4] = {};
  for (int s = 0; s < 4; ++s){
    if (s) __syncthreads();
    const int k0 = s*64;
    const ushort* srcA = (k0 < 128) ? (A0 + k0) : (A1 + (k0 - 128));
    #pragma unroll
    for (int i = 0; i < 4; ++i){
      int r = i*32 + lr16;
      int gr = row0 + r; if (gr >= N_NODE) gr = N_NODE-1;
      uint4 va = *(const uint4*)(srcA + (size_t)gr*128 + slot*8);
      *(uint4*)&As[r*64 + ((slot*8) ^ ((r&7)*8))] = va;
      uint4 vb = *(const uint4*)(W + r*256 + k0 + slot*8);
      *(uint4*)&Bs[r*64 + ((slot*8) ^ ((r&7)*8))] = vb;
    }
    __syncthreads();
    #pragma unroll
    for (int kk = 0; kk < 64; kk += 32){
      short8 af[4], bf[4];
      #pragma unroll
      for (int f = 0; f < 4; ++f){
        int ar = wr + f*16 + (l&15);
        af[f] = *(const short8*)&As[ar*64 + ((kk + (l>>4)*8) ^ ((ar&7)*8))];
        int bn = wc + f*16 + (l&15);
        bf[f] = *(const short8*)&Bs[bn*64 + ((kk + (l>>4)*8) ^ ((bn&7)*8))];
      }
      #pragma unroll
      for (int fi = 0; fi < 4; ++fi)
        #pragma unroll
        for (int fj = 0; fj < 4; ++fj)
          acc[fi][fj] = __builtin_amdgcn_mfma_f32_16x16x32_bf16(af[fi], bf[fj], acc[fi][fj], 0, 0, 0);
    }
  }
  const int g4 = (l>>4)*4;
  #pragma unroll
  for (int fi = 0; fi < 4; ++fi){
    #pragma unroll
    for (int r = 0; r < 4; ++r){
      int grow = row0 + wr + fi*16 + g4 + r;
      if (grow < N_NODE){
        #pragma unroll
        for (int fj = 0; fj < 4; ++fj){
          int col = wc + fj*16 + (l&15);
          float x = acc[fi][fj][r] + ba[col] + bb[col];
          unsigned pv2 = *(const unsigned*)&A1[(size_t)grow*128 + (col & ~1)];
          float v = (col & 1) ? bf_hi(pv2) : bf_lo(pv2);
          size_t o = (size_t)grow*128 + col;
          out[o] = emb[o] + sigf(x)*v + out[o];
        }
      }
    }
  }
}

__device__ __forceinline__ void user_final_body(int blk, ushort* As, ushort* Bs,
    const ushort* __restrict__ A0, const ushort* __restrict__ A1, const ushort* __restrict__ A2,
    const ushort* __restrict__ W,
    const float* __restrict__ bu,
    const float* __restrict__ ue, float* __restrict__ out)
{
  const int t = threadIdx.x;
  const int l = t & 63, wv = t >> 6;
  const int wr = (wv>>1)*64, wc = (wv&1)*64;
  const int row0 = blk*128;
  const int lr16 = t >> 3;
  const int slot = t & 7;
  f32x4 acc[4][4] = {};
  for (int s = 0; s < 6; ++s){
    if (s) __syncthreads();
    const int k0 = s*64;
    const ushort* base = (s < 2) ? A0 : ((s < 4) ? A1 : A2);
    const ushort* srcA = base + (s & 1)*64;
    #pragma unroll
    for (int i = 0; i < 4; ++i){
      int r = i*32 + lr16;
      int gr = row0 + r; if (gr >= N_USER) gr = N_USER-1;
      uint4 va = *(const uint4*)(srcA + (size_t)gr*128 + slot*8);
      *(uint4*)&As[r*64 + ((slot*8) ^ ((r&7)*8))] = va;
      uint4 vb = *(const uint4*)(W + r*384 + k0 + slot*8);
      *(uint4*)&Bs[r*64 + ((slot*8) ^ ((r&7)*8))] = vb;
    }
    __syncthreads();
    #pragma unroll
    for (int kk = 0; kk < 64; kk += 32){
      short8 af[4], bf[4];
      #pragma unroll
      for (int f = 0; f < 4; ++f){
        int ar = wr + f*16 + (l&15);
        af[f] = *(const short8*)&As[ar*64 + ((kk + (l>>4)*8) ^ ((ar&7)*8))];
        int bn = wc + f*16 + (l&15);
        bf[f] = *(const short8*)&Bs[bn*64 + ((kk + (l>>4)*8) ^ ((bn&7)*8))];
      }
      #pragma unroll
      for (int fi = 0; fi < 4; ++fi)
        #pragma unroll
        for (int fj = 0; fj < 4; ++fj)
          acc[fi][fj] = __builtin_amdgcn_mfma_f32_16x16x32_bf16(af[fi], bf[fj], acc[fi][fj], 0, 0, 0);
    }
  }
  const int g4 = (l>>4)*4;
  #pragma unroll
  for (int fi = 0; fi < 4; ++fi){
    #pragma unroll
    for (int r = 0; r < 4; ++r){
      int grow = row0 + wr + fi*16 + g4 + r;
      if (grow < N_USER){
        #pragma unroll
        for (int fj = 0; fj < 4; ++fj){
          int col = wc + fj*16 + (l&15);
          float g = sigf(acc[fi][fj][r] + bu[col]);
          unsigned e2 = *(const unsigned*)&A1[(size_t)grow*128 + (col & ~1)];
          float ei = (col & 1) ? bf_hi(e2) : bf_lo(e2);
          size_t o = (size_t)grow*128 + col;
          out[o] = g*ue[o] + (1.f - g)*ei;
        }
      }
    }
  }
}

__device__ __forceinline__ void price_final_body(int blk, float* A2,
    const float* __restrict__ pe, const float* __restrict__ num, const float* __restrict__ den,
    const float* __restrict__ mat_pv,
    const float* __restrict__ Wa, const float* __restrict__ ba,
    const float* __restrict__ Wb, const float* __restrict__ bb,
    float* __restrict__ out_price)
{
  int t = threadIdx.x;
  #pragma unroll
  for (int i = 0; i < 2; ++i){
    int flat = i*256 + t;
    int rl = flat >> 8; int k = flat & 255;
    int r = blk*2 + rl;
    float v;
    if (k < 128) v = pe[r*128 + k];
    else         v = num[r*128 + (k-128)] / (den[r] + 1e-8f) * mat_pv[r];
    A2[rl*256 + k] = v;
  }
  __syncthreads();
  int rl = t >> 7; int c = t & 127;
  int r = blk*2 + rl;
  float x = 0.f;
  #pragma unroll 4
  for (int k = 0; k < 256; ++k){
    float w = (k < 128) ? (Wa[c*256 + k] + Wb[c*128 + k]) : Wa[c*256 + k];
    x += A2[rl*256 + k]*w;
  }
  float g = sigf(x + ba[c] + bb[c]);
  out_price[r*128 + c] = pe[r*128 + c] + g*A2[rl*256 + 128 + c];
}

__global__ __launch_bounds__(256) void k_finals_all(
    const ushort* __restrict__ bemb, const ushort* __restrict__ vp_bf, const ushort* __restrict__ Wc,
    const float* __restrict__ b_aogi, const float* __restrict__ b_bgi1,
    const float* __restrict__ emb, float* __restrict__ out_item,
    const ushort* __restrict__ bue, const ushort* __restrict__ eitem_bf, const ushort* __restrict__ uvp_bf,
    const ushort* __restrict__ Wub, const float* __restrict__ b_user,
    const float* __restrict__ ue, float* __restrict__ out_user,
    const float* __restrict__ pe, const float* __restrict__ pv_num, const float* __restrict__ pv_den,
    const float* __restrict__ mat_pv,
    const float* __restrict__ W_aogp, const float* __restrict__ b_aogp,
    const float* __restrict__ W_bgp1, const float* __restrict__ b_bgp1,
    float* __restrict__ out_price)
{
  __shared__ __align__(16) ushort As[128*64];
  __shared__ __align__(16) ushort Bs[128*64];
  __shared__ float A2[512];
  int b = blockIdx.x;
  if (b < FB_ITEM){
    item_final_body(b, As, Bs, bemb, vp_bf, Wc, b_aogi, b_bgi1, emb, out_item);
  } else if (b < FB_ITEM + FB_USER){
    user_final_body(b - FB_ITEM, As, Bs, bue, eitem_bf, uvp_bf, Wub, b_user, ue, out_user);
  } else {
    price_final_body(b - FB_ITEM - FB_USER, A2, pe, pv_num, pv_den, mat_pv,
                     W_aogp, b_aogp, W_bgp1, b_bgp1, out_price);
  }
}

extern "C" void kernel_launch(void* const* d_in, const int* in_sizes, int n_in,
                              void* d_out, int out_size, void* d_ws, size_t ws_size,
                              hipStream_t stream){
  (void)in_sizes; (void)n_in; (void)out_size; (void)ws_size;
  const float* emb = (const float*)d_in[0];
  const float* pe  = (const float*)d_in[1];
  const float* ue  = (const float*)d_in[2];
  const int*   adj_r = (const int*)d_in[3];  const int* adj_c = (const int*)d_in[4];  const float* adj_v = (const float*)d_in[5];
  const int*   vp_r  = (const int*)d_in[6];  const int* vp_c  = (const int*)d_in[7];  const float* vp_v  = (const float*)d_in[8];
  const int*   vu_r  = (const int*)d_in[9];  const int* vu_c  = (const int*)d_in[10]; const float* vu_v  = (const float*)d_in[11];
  const int*   pv_r  = (const int*)d_in[12]; const int* pv_c  = (const int*)d_in[13]; const float* pv_v  = (const float*)d_in[14];
  const int*   uv_r  = (const int*)d_in[15]; const int* uv_c  = (const int*)d_in[16]; const float* uv_v  = (const float*)d_in[17];
  const int*   ipi   = (const int*)d_in[18];
  const float* mat_vu = (const float*)d_in[19];
  const float* mat_pv = (const float*)d_in[20];
  const float* mat_uv = (const float*)d_in[21];
  const float* W_aogi = (const float*)d_in[22]; const float* b_aogi = (const float*)d_in[23];
  const float* W_bgi1 = (const float*)d_in[24]; const float* b_bgi1 = (const float*)d_in[25];
  const float* W_aogp = (const float*)d_in[26]; const float* b_aogp = (const float*)d_in[27];
  const float* W_bgp1 = (const float*)d_in[28]; const float* b_bgp1 = (const float*)d_in[29];
  const float* W_user = (const float*)d_in[30]; const float* b_user = (const float*)d_in[31];
  const float* lam    = (const float*)d_in[32];

  float* out_item  = (float*)d_out;
  float* out_price = out_item + (size_t)N_NODE*EMB;
  float* out_user  = out_price + (size_t)N_PRICE*EMB;

  char* w = (char*)d_ws;
  size_t off = 0;
  auto alloc = [&](size_t bytes)->char*{
    char* p = w + off;
    off = (off + bytes + 255) & ~(size_t)255;
    return p;
  };
  int* fillPad  = (int*)alloc(2*FTOT*4);
  int* fillReal = fillPad + FTOT;
  int* aS  = (int*)alloc((N_NODE+1)*4);
  int* uS  = (int*)alloc((N_NODE+1)*4);
  int* vS  = (int*)alloc((N_USER+1)*4);
  int* pS  = (int*)alloc((N_NODE+1)*4);
  int* qS  = (int*)alloc(101*4);
  ushort* Wc_item = (ushort*)alloc(128*256*2);
  ushort* Wu_bf   = (ushort*)alloc(128*384*2);
  char* region = alloc((size_t)93*1024*1024);
  uint2* stgA = (uint2*)region;
  uint2* stgU = (uint2*)(region + (size_t)256*CAPA*8);
  uint2* stgV = (uint2*)(region + (size_t)2*256*CAPA*8);
  uint2* stgP = (uint2*)(region + (size_t)3*256*CAPA*8);
  uint2* stgQ = (uint2*)(region + (size_t)3*256*CAPA*8 + (size_t)256*1536*8);
  unsigned* bemb = (unsigned*)region;
  unsigned* bue  = (unsigned*)(region + (size_t)N_NODE*EMB*2);
  unsigned* bpe  = (unsigned*)(region + (size_t)(N_NODE+N_USER)*EMB*2);
  unsigned* vp_bf = (unsigned*)(region + (size_t)37*1024*1024);
  int2*  adjE = (int2*)alloc(((size_t)E_VV+16)*8);
  int2*  vuE  = (int2*)alloc(((size_t)E_VU+16)*8);
  int2*  uvE  = (int2*)alloc(((size_t)E_UV+16)*8);
  int2*  vpE  = (int2*)alloc(((size_t)E_VP+16)*8);
  int2*  pvE  = (int2*)alloc(((size_t)E_VP+16)*8);
  unsigned* eitem_bf = (unsigned*)alloc((size_t)N_USER*64*4);
  unsigned* uvp_bf   = (unsigned*)alloc((size_t)N_USER*64*4);
  float* pv_num   = (float*)alloc((size_t)N_PRICE*EMB*4);
  float* pv_den   = (float*)alloc(N_PRICE*4);

  // 1) weight prep + zero fills + zero sentinels
  k_prep<<<321,256,0,stream>>>(W_aogi, W_bgi1, W_user, Wc_item, Wu_bf,
                               fillPad, adjE, vuE, uvE, vpE, pvE);

  // 2) Pass A: bucket all 5 edge lists, 128B-aligned chunks
  k_bucket_all<<<BKT,256,0,stream>>>(
      adj_r,adj_c,adj_v, vu_r,vu_c,vu_v, uv_r,uv_c,uv_v, vp_r,vp_c,vp_v, pv_r,pv_c,pv_v,
      fillPad, fillReal, stgA, stgU, stgV, stgP, stgQ);

  // 3) Pass B: CSR finalize, col-grouped, compact coalesced flush
  k_csr_all<<<CBT,256,0,stream>>>(stgA, stgU, stgV, stgP, stgQ, fillPad, fillReal,
      aS, uS, vS, pS, qS, adjE, vuE, uvE, vpE, pvE);

  // 4) bf16 table conversion (overlays dead staging)
  k_cvt_all<<<((N_NODE+N_USER+N_PRICE)*EMB/4+255)/256,256,0,stream>>>(
      (const float4*)emb, (const float4*)ue, (const float4*)pe,
      (uint2*)bemb, (uint2*)bue, (uint2*)bpe);

  // 5) all row-owned SpMMs in one launch (pv blocks first)
  k_rows_all<<<RBT,256,0,stream>>>(
      (const uint4*)bemb, (const uint4*)bue, (const uint4*)bpe,
      aS, adjE, uS, vuE, pS, vpE, vS, uvE, qS, pvE,
      ipi, mat_vu, mat_uv, lam,
      (float4*)out_item, (uint4*)vp_bf, (uint4*)eitem_bf, (uint4*)uvp_bf,
      pv_num, pv_den);

  // 6) all finals in one launch
  k_finals_all<<<FBT,256,0,stream>>>(
      (const ushort*)bemb, (const ushort*)vp_bf, Wc_item, b_aogi, b_bgi1, emb, out_item,
      (const ushort*)bue, (const ushort*)eitem_bf, (const ushort*)uvp_bf, Wu_bf, b_user, ue, out_user,
      pe, pv_num, pv_den, mat_pv, W_aogp, b_aogp, W_bgp1, b_bgp1, out_price);
}

// Round 12
// 543.081 us; speedup vs baseline: 1.3268x; 1.3268x over previous
//
#include <hip/hip_runtime.h>
#include <hip/hip_bf16.h>

#define N_NODE 100000
#define N_USER 40000
#define N_PRICE 100
#define EMB 128
#define E_VV 2000000
#define E_VP 200000
#define E_VU 2000000
#define E_UV 2000000

#define FOFF0 0
#define FOFF1 256
#define FOFF2 512
#define FOFF3 767
#define FOFF4 1023
#define FTOT  1073
#define EPB   8192
#define BK1 245
#define BK2 490
#define BK3 735
#define BK4 760
#define BKT 785
#define CB1 256
#define CB2 512
#define CB3 767
#define CB4 1023
#define CBT 1073
#define RB_PV   100
#define RB_ITEM 25000
#define RB_USER 10000
#define RBT (RB_PV + RB_ITEM + RB_USER)
#define FB_ITEM 782
#define FB_USER 313
#define FBT (FB_ITEM + FB_USER + 50)

typedef __attribute__((ext_vector_type(8))) short short8;
typedef __attribute__((ext_vector_type(4))) float f32x4;

__device__ __forceinline__ float sigf(float x){ return 1.f/(1.f+__expf(-x)); }
__device__ __forceinline__ unsigned bfr(float f){
  unsigned u = __float_as_uint(f);
  return (u + 0x7FFFu + ((u>>16)&1u)) >> 16;
}
__device__ __forceinline__ float bf_lo(unsigned u){ return __uint_as_float(u << 16); }
__device__ __forceinline__ float bf_hi(unsigned u){ return __uint_as_float(u & 0xFFFF0000u); }
__device__ __forceinline__ unsigned pack2(float x, float y){ return bfr(x) | (bfr(y)<<16); }

// ---------------- fused f32 -> packed bf16 convert (all 3 tables) ----------------
__global__ __launch_bounds__(256) void k_cvt_all(
    const float4* __restrict__ se, const float4* __restrict__ su, const float4* __restrict__ sp,
    uint2* __restrict__ de, uint2* __restrict__ du, uint2* __restrict__ dp){
  const int nE = N_NODE*EMB/4, nU = N_USER*EMB/4, nP = N_PRICE*EMB/4;
  int i = blockIdx.x*256 + threadIdx.x;
  const float4* src; uint2* dst; int j;
  if (i < nE){ src = se; dst = de; j = i; }
  else if (i < nE+nU){ src = su; dst = du; j = i-nE; }
  else if (i < nE+nU+nP){ src = sp; dst = dp; j = i-nE-nU; }
  else return;
  float4 v = src[j];
  dst[j] = make_uint2(bfr(v.x) | (bfr(v.y)<<16), bfr(v.z) | (bfr(v.w)<<16));
}

// ---------------- prep: bf16 weights + zero fill + zero sentinels ----------------
__global__ __launch_bounds__(256) void k_prep(
    const float* __restrict__ Wa, const float* __restrict__ Wb, const float* __restrict__ Wu,
    ushort* __restrict__ Wc, ushort* __restrict__ Wub,
    int* __restrict__ fill,
    int2* __restrict__ adjE, int2* __restrict__ vuE, int2* __restrict__ uvE,
    int2* __restrict__ vpE, int2* __restrict__ pvE){
  if (blockIdx.x == 320){
    int t = threadIdx.x;
    for (int i = t; i < FTOT; i += 256) fill[i] = 0;
    if (t < 16){
      int2 z = make_int2(0,0);
      adjE[E_VV+t] = z; vuE[E_VU+t] = z; uvE[E_UV+t] = z; vpE[E_VP+t] = z; pvE[E_VP+t] = z;
    }
    return;
  }
  int idx = blockIdx.x*256 + threadIdx.x;
  if (idx < 128*256){
    int n = idx >> 8, k = idx & 255;
    float v = Wa[n*256+k] + ((k < 128) ? Wb[n*128+k] : 0.f);
    Wc[idx] = (ushort)bfr(v);
  } else {
    int j = idx - 128*256;
    if (j < 128*384) Wub[j] = (ushort)bfr(Wu[j]);
  }
}

// ---------------- Pass A: LDS counting-sort bucket, bursty coalesced flush ----------------
template<int E, int RPB, int NB, int CAPc>
__device__ __forceinline__ void bucket_body(int blk,
    const int* __restrict__ rows, const int* __restrict__ cols, const float* __restrict__ vals,
    int* __restrict__ fill, uint2* __restrict__ stg,
    int* cnt, int* gbase, int* lbase, uint2* stage)
{
  const int t = threadIdx.x;
  const int e0 = blk * EPB;
  for (int i = t; i < NB; i += 256) cnt[i] = 0;
  __syncthreads();
  #pragma unroll 4
  for (int i = 0; i < 32; ++i){
    int e = e0 + i*256 + t;
    if (e < E) atomicAdd(&cnt[rows[e]/RPB], 1);
  }
  __syncthreads();
  if (t < 64){   // exclusive scan cnt -> lbase
    int run = 0;
    for (int c0 = 0; c0 < NB; c0 += 64){
      int j = c0 + t;
      int x = (j < NB) ? cnt[j] : 0;
      int s = x;
      #pragma unroll
      for (int d = 1; d < 64; d <<= 1){ int y = __shfl_up(s, d); if (t >= d) s += y; }
      if (j < NB) lbase[j] = run + s - x;
      run += __shfl(s, 63);
    }
  }
  __syncthreads();
  for (int b = t; b < NB; b += 256){
    int c = cnt[b];
    gbase[b] = (c > 0) ? atomicAdd(&fill[b], c) : 0;
    cnt[b] = lbase[b];        // becomes local cursor
  }
  __syncthreads();
  #pragma unroll 4
  for (int i = 0; i < 32; ++i){
    int e = e0 + i*256 + t;
    if (e < E){
      int r = rows[e];
      int b = r/RPB, rl = r - b*RPB;
      int pos = atomicAdd(&cnt[b], 1);
      stage[pos] = make_uint2((unsigned)cols[e] | ((unsigned)rl << 17), __float_as_uint(vals[e]));
    }
  }
  __syncthreads();
  const int wid = t >> 6, lane = t & 63;
  for (int b = wid; b < NB; b += 4){
    int lb = lbase[b];
    int n = cnt[b] - lb;
    int gb = gbase[b];
    for (int j = lane; j < n; j += 64){
      int slot = gb + j; if (slot >= CAPc) slot = CAPc - 1;
      stg[(size_t)b*CAPc + slot] = stage[lb + j];
    }
  }
}

__global__ __launch_bounds__(256) void k_bucket_all(
    const int* __restrict__ aR, const int* __restrict__ aC, const float* __restrict__ aV,
    const int* __restrict__ uR, const int* __restrict__ uC, const float* __restrict__ uV,
    const int* __restrict__ vR, const int* __restrict__ vC, const float* __restrict__ vV,
    const int* __restrict__ pR, const int* __restrict__ pC, const float* __restrict__ pV,
    const int* __restrict__ qR, const int* __restrict__ qC, const float* __restrict__ qV,
    int* __restrict__ fill,
    uint2* __restrict__ stgA, uint2* __restrict__ stgU, uint2* __restrict__ stgV,
    uint2* __restrict__ stgP, uint2* __restrict__ stgQ)
{
  __shared__ int cnt[256], gbase[256], lbase[256];
  __shared__ uint2 stage[EPB];
  int b = blockIdx.x;
  if      (b < BK1) bucket_body<E_VV,391,256,8704>(b,      aR,aC,aV, fill+FOFF0, stgA, cnt, gbase, lbase, stage);
  else if (b < BK2) bucket_body<E_VU,391,256,8704>(b-BK1,  uR,uC,uV, fill+FOFF1, stgU, cnt, gbase, lbase, stage);
  else if (b < BK3) bucket_body<E_UV,157,255,8704>(b-BK2,  vR,vC,vV, fill+FOFF2, stgV, cnt, gbase, lbase, stage);
  else if (b < BK4) bucket_body<E_VP,391,256,1536>(b-BK3,  pR,pC,pV, fill+FOFF3, stgP, cnt, gbase, lbase, stage);
  else              bucket_body<E_VP,  2, 50,5120>(b-BK4,  qR,qC,qV, fill+FOFF4, stgQ, cnt, gbase, lbase, stage);
}

// ---------------- Pass B: CSR finalize via LDS stage (no sort), coalesced flush (R10) ----------------
template<int NROW, int RPB, int NB, int CAPc>
__device__ __forceinline__ void csr_body(int b,
    const uint2* __restrict__ stg, const int* __restrict__ fill,
    int* __restrict__ start, int2* __restrict__ csr,
    int* cnt, uint2* stage, int* sbase)
{
  const int t = threadIdx.x;
  const int row0 = b * RPB;
  int R = NROW - row0; if (R > RPB) R = RPB;
  int count = fill[b]; if (count > CAPc) count = CAPc;
  for (int i = t; i < R; i += 256) cnt[i] = 0;
  if (t < 64){
    int run = 0;
    for (int c0 = 0; c0 < NB; c0 += 64){
      int j = c0 + t;
      int x = (j < NB) ? fill[j] : 0;
      int s = x;
      #pragma unroll
      for (int d = 1; d < 64; d <<= 1){ int y = __shfl_up(s, d); if (t >= d) s += y; }
      if (j == b) *sbase = run + s - x;
      run += __shfl(s, 63);
    }
  }
  __syncthreads();
  const int base = *sbase;
  const uint2* mystg = stg + (size_t)b*CAPc;
  for (int j = t; j < count; j += 256)
    atomicAdd(&cnt[mystg[j].x >> 17], 1);
  __syncthreads();
  if (t < 64){
    int run = 0;
    for (int c0 = 0; c0 < R; c0 += 64){
      int i = c0 + t;
      int x = (i < R) ? cnt[i] : 0;
      int s = x;
      #pragma unroll
      for (int d = 1; d < 64; d <<= 1){ int y = __shfl_up(s, d); if (t >= d) s += y; }
      if (i < R) cnt[i] = run + s - x;
      run += __shfl(s, 63);
    }
  }
  __syncthreads();
  for (int i = t; i < R; i += 256) start[row0 + i] = base + cnt[i];
  if (b == NB-1 && t == 0) start[NROW] = base + count;
  __syncthreads();
  for (int j = t; j < count; j += 256){
    uint2 kv = mystg[j];
    int rl = kv.x >> 17;
    int pos = atomicAdd(&cnt[rl], 1);
    stage[pos] = kv;
  }
  __syncthreads();
  for (int j = t; j < count; j += 256){
    uint2 kv = stage[j];
    csr[base + j] = make_int2((int)(kv.x & 0x1FFFF), (int)kv.y);
  }
}

__global__ __launch_bounds__(256) void k_csr_all(
    const uint2* __restrict__ stgA, const uint2* __restrict__ stgU, const uint2* __restrict__ stgV,
    const uint2* __restrict__ stgP, const uint2* __restrict__ stgQ,
    const int* __restrict__ fill,
    int* __restrict__ aS, int* __restrict__ uS, int* __restrict__ vS,
    int* __restrict__ pS, int* __restrict__ qS,
    int2* __restrict__ aE, int2* __restrict__ uE, int2* __restrict__ vE,
    int2* __restrict__ pE, int2* __restrict__ qE)
{
  __shared__ int cnt[391];
  __shared__ int sbase;
  __shared__ uint2 stage[8704];
  int b = blockIdx.x;
  if      (b < CB1) csr_body<N_NODE,391,256,8704>(b,     stgA, fill+FOFF0, aS, aE, cnt, stage, &sbase);
  else if (b < CB2) csr_body<N_NODE,391,256,8704>(b-CB1, stgU, fill+FOFF1, uS, uE, cnt, stage, &sbase);
  else if (b < CB3) csr_body<N_USER,157,255,8704>(b-CB2, stgV, fill+FOFF2, vS, vE, cnt, stage, &sbase);
  else if (b < CB4) csr_body<N_NODE,391,256,1536>(b-CB3, stgP, fill+FOFF3, pS, pE, cnt, stage, &sbase);
  else              csr_body<N_PRICE,  2, 50,5120>(b-CB4, stgQ, fill+FOFF4, qS, qE, cnt, stage, &sbase);
}

// ======== row SpMMs: 16 lanes/edge, uint4 gathers (unchanged) ========

#define FMA8(ACC, U, V)                                     \
  ACC[0] += (V)*bf_lo((U).x); ACC[1] += (V)*bf_hi((U).x);   \
  ACC[2] += (V)*bf_lo((U).y); ACC[3] += (V)*bf_hi((U).y);   \
  ACC[4] += (V)*bf_lo((U).z); ACC[5] += (V)*bf_hi((U).z);   \
  ACC[6] += (V)*bf_lo((U).w); ACC[7] += (V)*bf_hi((U).w);

#define RED8(ACC)                                           \
  _Pragma("unroll")                                         \
  for (int j = 0; j < 8; ++j){                              \
    ACC[j] += __shfl_xor(ACC[j], 16);                       \
    ACC[j] += __shfl_xor(ACC[j], 32);                       \
  }

__device__ __forceinline__ void item_body(int rb,
    const uint4* __restrict__ be4, const uint4* __restrict__ bu4, const uint4* __restrict__ bp4,
    const int* __restrict__ aS, const int2* __restrict__ aE,
    const int* __restrict__ uS, const int2* __restrict__ uE,
    const int* __restrict__ pS, const int2* __restrict__ pE,
    const float* __restrict__ mat_vu, const float* __restrict__ lam,
    float4* __restrict__ out4, uint4* __restrict__ vp4)
{
  const int r = rb*4 + (threadIdx.x >> 6);
  const int l = threadIdx.x & 63;
  const int g = l >> 4, q = l & 15;
  float aA[8] = {}, aU[8] = {}, aP[8] = {};
  float den = 0.f;
  int s = aS[r], e = aS[r+1];
  for (int i = s; i < e; i += 16){
    int2 cv[4]; uint4 u[4];
    #pragma unroll
    for (int k = 0; k < 4; ++k) cv[k] = aE[i + 4*k + g];
    #pragma unroll
    for (int k = 0; k < 4; ++k) u[k] = be4[(size_t)cv[k].x*16 + q];
    #pragma unroll
    for (int k = 0; k < 4; ++k){
      float v = (i + 4*k + g < e) ? __int_as_float(cv[k].y) : 0.f;
      FMA8(aA, u[k], v)
    }
  }
  s = uS[r]; e = uS[r+1];
  for (int i = s; i < e; i += 16){
    int2 cv[4]; uint4 u[4];
    #pragma unroll
    for (int k = 0; k < 4; ++k) cv[k] = uE[i + 4*k + g];
    #pragma unroll
    for (int k = 0; k < 4; ++k) u[k] = bu4[(size_t)cv[k].x*16 + q];
    #pragma unroll
    for (int k = 0; k < 4; ++k){
      float v = (i + 4*k + g < e) ? __int_as_float(cv[k].y) : 0.f;
      FMA8(aU, u[k], v)
      den += v;
    }
  }
  s = pS[r]; e = pS[r+1];
  for (int i = s; i < e; i += 16){
    int2 cv[4]; uint4 u[4];
    #pragma unroll
    for (int k = 0; k < 4; ++k) cv[k] = pE[i + 4*k + g];
    #pragma unroll
    for (int k = 0; k < 4; ++k) u[k] = bp4[(size_t)cv[k].x*16 + q];
    #pragma unroll
    for (int k = 0; k < 4; ++k){
      float v = (i + 4*k + g < e) ? __int_as_float(cv[k].y) : 0.f;
      FMA8(aP, u[k], v)
    }
  }
  RED8(aA) RED8(aU) RED8(aP)
  den += __shfl_xor(den, 16); den += __shfl_xor(den, 32);
  float sc = lam[0]*mat_vu[r]/(den + 1e-8f);
  if (g == 0){
    out4[(size_t)r*32 + q*2]     = make_float4(aA[0]+sc*aU[0], aA[1]+sc*aU[1], aA[2]+sc*aU[2], aA[3]+sc*aU[3]);
    out4[(size_t)r*32 + q*2 + 1] = make_float4(aA[4]+sc*aU[4], aA[5]+sc*aU[5], aA[6]+sc*aU[6], aA[7]+sc*aU[7]);
    vp4[(size_t)r*16 + q] = make_uint4(pack2(aP[0],aP[1]), pack2(aP[2],aP[3]), pack2(aP[4],aP[5]), pack2(aP[6],aP[7]));
  }
}

__device__ __forceinline__ void user_body(int rb,
    const uint4* __restrict__ be4, const uint4* __restrict__ bp4,
    const int* __restrict__ S, const int2* __restrict__ E,
    const int* __restrict__ ipi, const float* __restrict__ mat_uv,
    uint4* __restrict__ eit4, uint4* __restrict__ uvp4)
{
  const int r = rb*4 + (threadIdx.x >> 6);
  const int l = threadIdx.x & 63;
  const int g = l >> 4, q = l & 15;
  float aI[8] = {}, aP[8] = {};
  float den = 0.f;
  int s = S[r], e = S[r+1];
  for (int i = s; i < e; i += 8){
    int2 cv[2];
    #pragma unroll
    for (int k = 0; k < 2; ++k) cv[k] = E[i + 4*k + g];
    uint4 u[2]; int ip[2];
    #pragma unroll
    for (int k = 0; k < 2; ++k){ u[k] = be4[(size_t)cv[k].x*16 + q]; ip[k] = ipi[cv[k].x]; }
    uint4 y[2];
    #pragma unroll
    for (int k = 0; k < 2; ++k) y[k] = bp4[(size_t)ip[k]*16 + q];
    #pragma unroll
    for (int k = 0; k < 2; ++k){
      float v = (i + 4*k + g < e) ? __int_as_float(cv[k].y) : 0.f;
      FMA8(aI, u[k], v)
      FMA8(aP, y[k], v)
      den += v;
    }
  }
  RED8(aI) RED8(aP)
  den += __shfl_xor(den, 16); den += __shfl_xor(den, 32);
  float sc = mat_uv[r]/(den + 1e-8f);
  if (g == 0){
    eit4[(size_t)r*16 + q] = make_uint4(pack2(sc*aI[0],sc*aI[1]), pack2(sc*aI[2],sc*aI[3]),
                                        pack2(sc*aI[4],sc*aI[5]), pack2(sc*aI[6],sc*aI[7]));
    uvp4[(size_t)r*16 + q] = make_uint4(pack2(aP[0],aP[1]), pack2(aP[2],aP[3]),
                                        pack2(aP[4],aP[5]), pack2(aP[6],aP[7]));
  }
}

__device__ __forceinline__ void pv_body(int r,
    const uint4* __restrict__ be4, const int2* __restrict__ E, const int* __restrict__ S,
    float* __restrict__ num, float* __restrict__ den_out)
{
  const int t = threadIdx.x;
  const int wid = t >> 6, l = t & 63;
  const int g = l >> 4, q = l & 15;
  float aP[8] = {}; float den = 0.f;
  int s = S[r], e = S[r+1];
  for (int i0 = s + wid*16; i0 < e; i0 += 64){
    int2 cv[4]; uint4 u[4];
    #pragma unroll
    for (int k = 0; k < 4; ++k) cv[k] = E[i0 + 4*k + g];
    #pragma unroll
    for (int k = 0; k < 4; ++k) u[k] = be4[(size_t)cv[k].x*16 + q];
    #pragma unroll
    for (int k = 0; k < 4; ++k){
      float v = (i0 + 4*k + g < e) ? __int_as_float(cv[k].y) : 0.f;
      FMA8(aP, u[k], v)
      den += v;
    }
  }
  RED8(aP)
  den += __shfl_xor(den, 16); den += __shfl_xor(den, 32);
  __shared__ float red[4][16][8];
  __shared__ float dred[4];
  if (g == 0){
    #pragma unroll
    for (int j = 0; j < 8; ++j) red[wid][q][j] = aP[j];
    if (l == 0) dred[wid] = den;
  }
  __syncthreads();
  if (t < 16){
    #pragma unroll
    for (int j = 0; j < 8; ++j)
      num[r*128 + t*8 + j] = red[0][t][j] + red[1][t][j] + red[2][t][j] + red[3][t][j];
    if (t == 0) den_out[r] = dred[0] + dred[1] + dred[2] + dred[3];
  }
}

__global__ __launch_bounds__(256) void k_rows_all(
    const uint4* __restrict__ be4, const uint4* __restrict__ bu4, const uint4* __restrict__ bp4,
    const int* __restrict__ aS, const int2* __restrict__ aE,
    const int* __restrict__ uS, const int2* __restrict__ uE,
    const int* __restrict__ pS, const int2* __restrict__ pE,
    const int* __restrict__ vS, const int2* __restrict__ vE,
    const int* __restrict__ qS, const int2* __restrict__ qE,
    const int* __restrict__ ipi,
    const float* __restrict__ mat_vu, const float* __restrict__ mat_uv, const float* __restrict__ lam,
    float4* __restrict__ out4, uint4* __restrict__ vp4,
    uint4* __restrict__ eit4, uint4* __restrict__ uvp4,
    float* __restrict__ pv_num, float* __restrict__ pv_den)
{
  int b = blockIdx.x;
  if (b < RB_PV){ pv_body(b, be4, qE, qS, pv_num, pv_den); return; }
  b -= RB_PV;
  if (b < RB_ITEM){ item_body(b, be4, bu4, bp4, aS, aE, uS, uE, pS, pE, mat_vu, lam, out4, vp4); return; }
  b -= RB_ITEM;
  user_body(b, be4, bp4, vS, vE, ipi, mat_uv, eit4, uvp4);
}

// ======== finals (epilogues read bf16 tables instead of f32) ========
__device__ __forceinline__ void item_final_body(int blk, ushort* As, ushort* Bs,
    const ushort* __restrict__ A0, const ushort* __restrict__ A1,
    const ushort* __restrict__ W,
    const float* __restrict__ ba, const float* __restrict__ bb,
    float* __restrict__ out)
{
  const int t = threadIdx.x;
  const int l = t & 63, wv = t >> 6;
  const int wr = (wv>>1)*64, wc = (wv&1)*64;
  const int row0 = blk*128;
  const int lr16 = t >> 3;
  const int slot = t & 7;
  f32x4 acc[4][4] = {};
  for (int s = 0; s < 4; ++s){
    if (s) __syncthreads();
    const int k0 = s*64;
    const ushort* srcA = (k0 < 128) ? (A0 + k0) : (A1 + (k0 - 128));
    #pragma unroll
    for (int i = 0; i < 4; ++i){
      int r = i*32 + lr16;
      int gr = row0 + r; if (gr >= N_NODE) gr = N_NODE-1;
      uint4 va = *(const uint4*)(srcA + (size_t)gr*128 + slot*8);
      *(uint4*)&As[r*64 + ((slot*8) ^ ((r&7)*8))] = va;
      uint4 vb = *(const uint4*)(W + r*256 + k0 + slot*8);
      *(uint4*)&Bs[r*64 + ((slot*8) ^ ((r&7)*8))] = vb;
    }
    __syncthreads();
    #pragma unroll
    for (int kk = 0; kk < 64; kk += 32){
      short8 af[4], bf[4];
      #pragma unroll
      for (int f = 0; f < 4; ++f){
        int ar = wr + f*16 + (l&15);
        af[f] = *(const short8*)&As[ar*64 + ((kk + (l>>4)*8) ^ ((ar&7)*8))];
        int bn = wc + f*16 + (l&15);
        bf[f] = *(const short8*)&Bs[bn*64 + ((kk + (l>>4)*8) ^ ((bn&7)*8))];
      }
      #pragma unroll
      for (int fi = 0; fi < 4; ++fi)
        #pragma unroll
        for (int fj = 0; fj < 4; ++fj)
          acc[fi][fj] = __builtin_amdgcn_mfma_f32_16x16x32_bf16(af[fi], bf[fj], acc[fi][fj], 0, 0, 0);
    }
  }
  const int g4 = (l>>4)*4;
  #pragma unroll
  for (int fi = 0; fi < 4; ++fi){
    #pragma unroll
    for (int r = 0; r < 4; ++r){
      int grow = row0 + wr + fi*16 + g4 + r;
      if (grow < N_NODE){
        #pragma unroll
        for (int fj = 0; fj < 4; ++fj){
          int col = wc + fj*16 + (l&15);
          float x = acc[fi][fj][r] + ba[col] + bb[col];
          unsigned pv2 = *(const unsigned*)&A1[(size_t)grow*128 + (col & ~1)];
          float v = (col & 1) ? bf_hi(pv2) : bf_lo(pv2);
          unsigned em2 = *(const unsigned*)&A0[(size_t)grow*128 + (col & ~1)];
          float em = (col & 1) ? bf_hi(em2) : bf_lo(em2);
          size_t o = (size_t)grow*128 + col;
          out[o] = em + sigf(x)*v + out[o];
        }
      }
    }
  }
}

__device__ __forceinline__ void user_final_body(int blk, ushort* As, ushort* Bs,
    const ushort* __restrict__ A0, const ushort* __restrict__ A1, const ushort* __restrict__ A2,
    const ushort* __restrict__ W,
    const float* __restrict__ bu,
    float* __restrict__ out)
{
  const int t = threadIdx.x;
  const int l = t & 63, wv = t >> 6;
  const int wr = (wv>>1)*64, wc = (wv&1)*64;
  const int row0 = blk*128;
  const int lr16 = t >> 3;
  const int slot = t & 7;
  f32x4 acc[4][4] = {};
  for (int s = 0; s < 6; ++s){
    if (s) __syncthreads();
    const int k0 = s*64;
    const ushort* base = (s < 2) ? A0 : ((s < 4) ? A1 : A2);
    const ushort* srcA = base + (s & 1)*64;
    #pragma unroll
    for (int i = 0; i < 4; ++i){
      int r = i*32 + lr16;
      int gr = row0 + r; if (gr >= N_USER) gr = N_USER-1;
      uint4 va = *(const uint4*)(srcA + (size_t)gr*128 + slot*8);
      *(uint4*)&As[r*64 + ((slot*8) ^ ((r&7)*8))] = va;
      uint4 vb = *(const uint4*)(W + r*384 + k0 + slot*8);
      *(uint4*)&Bs[r*64 + ((slot*8) ^ ((r&7)*8))] = vb;
    }
    __syncthreads();
    #pragma unroll
    for (int kk = 0; kk < 64; kk += 32){
      short8 af[4], bf[4];
      #pragma unroll
      for (int f = 0; f < 4; ++f){
        int ar = wr + f*16 + (l&15);
        af[f] = *(const short8*)&As[ar*64 + ((kk + (l>>4)*8) ^ ((ar&7)*8))];
        int bn = wc + f*16 + (l&15);
        bf[f] = *(const short8*)&Bs[bn*64 + ((kk + (l>>4)*8) ^ ((bn&7)*8))];
      }
      #pragma unroll
      for (int fi = 0; fi < 4; ++fi)
        #pragma unroll
        for (int fj = 0; fj < 4; ++fj)
          acc[fi][fj] = __builtin_amdgcn_mfma_f32_16x16x32_bf16(af[fi], bf[fj], acc[fi][fj], 0, 0, 0);
    }
  }
  const int g4 = (l>>4)*4;
  #pragma unroll
  for (int fi = 0; fi < 4; ++fi){
    #pragma unroll
    for (int r = 0; r < 4; ++r){
      int grow = row0 + wr + fi*16 + g4 + r;
      if (grow < N_USER){
        #pragma unroll
        for (int fj = 0; fj < 4; ++fj){
          int col = wc + fj*16 + (l&15);
          float g = sigf(acc[fi][fj][r] + bu[col]);
          unsigned e2 = *(const unsigned*)&A1[(size_t)grow*128 + (col & ~1)];
          float ei = (col & 1) ? bf_hi(e2) : bf_lo(e2);
          unsigned u2 = *(const unsigned*)&A0[(size_t)grow*128 + (col & ~1)];
          float uu = (col & 1) ? bf_hi(u2) : bf_lo(u2);
          size_t o = (size_t)grow*128 + col;
          out[o] = g*uu + (1.f - g)*ei;
        }
      }
    }
  }
}

__device__ __forceinline__ void price_final_body(int blk, float* A2,
    const float* __restrict__ pe, const float* __restrict__ num, const float* __restrict__ den,
    const float* __restrict__ mat_pv,
    const float* __restrict__ Wa, const float* __restrict__ ba,
    const float* __restrict__ Wb, const float* __restrict__ bb,
    float* __restrict__ out_price)
{
  int t = threadIdx.x;
  #pragma unroll
  for (int i = 0; i < 2; ++i){
    int flat = i*256 + t;
    int rl = flat >> 8; int k = flat & 255;
    int r = blk*2 + rl;
    float v;
    if (k < 128) v = pe[r*128 + k];
    else         v = num[r*128 + (k-128)] / (den[r] + 1e-8f) * mat_pv[r];
    A2[rl*256 + k] = v;
  }
  __syncthreads();
  int rl = t >> 7; int c = t & 127;
  int r = blk*2 + rl;
  float x = 0.f;
  #pragma unroll 4
  for (int k = 0; k < 256; ++k){
    float w = (k < 128) ? (Wa[c*256 + k] + Wb[c*128 + k]) : Wa[c*256 + k];
    x += A2[rl*256 + k]*w;
  }
  float g = sigf(x + ba[c] + bb[c]);
  out_price[r*128 + c] = pe[r*128 + c] + g*A2[rl*256 + 128 + c];
}

__global__ __launch_bounds__(256) void k_finals_all(
    const ushort* __restrict__ bemb, const ushort* __restrict__ vp_bf, const ushort* __restrict__ Wc,
    const float* __restrict__ b_aogi, const float* __restrict__ b_bgi1,
    float* __restrict__ out_item,
    const ushort* __restrict__ bue, const ushort* __restrict__ eitem_bf, const ushort* __restrict__ uvp_bf,
    const ushort* __restrict__ Wub, const float* __restrict__ b_user,
    float* __restrict__ out_user,
    const float* __restrict__ pe, const float* __restrict__ pv_num, const float* __restrict__ pv_den,
    const float* __restrict__ mat_pv,
    const float* __restrict__ W_aogp, const float* __restrict__ b_aogp,
    const float* __restrict__ W_bgp1, const float* __restrict__ b_bgp1,
    float* __restrict__ out_price)
{
  __shared__ __align__(16) ushort As[128*64];
  __shared__ __align__(16) ushort Bs[128*64];
  __shared__ float A2[512];
  int b = blockIdx.x;
  if (b < FB_ITEM){
    item_final_body(b, As, Bs, bemb, vp_bf, Wc, b_aogi, b_bgi1, out_item);
  } else if (b < FB_ITEM + FB_USER){
    user_final_body(b - FB_ITEM, As, Bs, bue, eitem_bf, uvp_bf, Wub, b_user, out_user);
  } else {
    price_final_body(b - FB_ITEM - FB_USER, A2, pe, pv_num, pv_den, mat_pv,
                     W_aogp, b_aogp, W_bgp1, b_bgp1, out_price);
  }
}

extern "C" void kernel_launch(void* const* d_in, const int* in_sizes, int n_in,
                              void* d_out, int out_size, void* d_ws, size_t ws_size,
                              hipStream_t stream){
  (void)in_sizes; (void)n_in; (void)out_size; (void)ws_size;
  const float* emb = (const float*)d_in[0];
  const float* pe  = (const float*)d_in[1];
  const float* ue  = (const float*)d_in[2];
  const int*   adj_r = (const int*)d_in[3];  const int* adj_c = (const int*)d_in[4];  const float* adj_v = (const float*)d_in[5];
  const int*   vp_r  = (const int*)d_in[6];  const int* vp_c  = (const int*)d_in[7];  const float* vp_v  = (const float*)d_in[8];
  const int*   vu_r  = (const int*)d_in[9];  const int* vu_c  = (const int*)d_in[10]; const float* vu_v  = (const float*)d_in[11];
  const int*   pv_r  = (const int*)d_in[12]; const int* pv_c  = (const int*)d_in[13]; const float* pv_v  = (const float*)d_in[14];
  const int*   uv_r  = (const int*)d_in[15]; const int* uv_c  = (const int*)d_in[16]; const float* uv_v  = (const float*)d_in[17];
  const int*   ipi   = (const int*)d_in[18];
  const float* mat_vu = (const float*)d_in[19];
  const float* mat_pv = (const float*)d_in[20];
  const float* mat_uv = (const float*)d_in[21];
  const float* W_aogi = (const float*)d_in[22]; const float* b_aogi = (const float*)d_in[23];
  const float* W_bgi1 = (const float*)d_in[24]; const float* b_bgi1 = (const float*)d_in[25];
  const float* W_aogp = (const float*)d_in[26]; const float* b_aogp = (const float*)d_in[27];
  const float* W_bgp1 = (const float*)d_in[28]; const float* b_bgp1 = (const float*)d_in[29];
  const float* W_user = (const float*)d_in[30]; const float* b_user = (const float*)d_in[31];
  const float* lam    = (const float*)d_in[32];

  float* out_item  = (float*)d_out;
  float* out_price = out_item + (size_t)N_NODE*EMB;
  float* out_user  = out_price + (size_t)N_PRICE*EMB;

  char* w = (char*)d_ws;
  size_t off = 0;
  auto alloc = [&](size_t bytes)->char*{
    char* p = w + off;
    off = (off + bytes + 255) & ~(size_t)255;
    return p;
  };
  int* fill = (int*)alloc(FTOT*4);
  int* aS  = (int*)alloc((N_NODE+1)*4);
  int* uS  = (int*)alloc((N_NODE+1)*4);
  int* vS  = (int*)alloc((N_USER+1)*4);
  int* pS  = (int*)alloc((N_NODE+1)*4);
  int* qS  = (int*)alloc(101*4);
  ushort* Wc_item = (ushort*)alloc(128*256*2);
  ushort* Wu_bf   = (ushort*)alloc(128*384*2);
  char* region = alloc((size_t)93*1024*1024);
  uint2* stgA = (uint2*)region;
  uint2* stgU = (uint2*)(region + (size_t)256*8704*8);
  uint2* stgV = (uint2*)(region + (size_t)2*256*8704*8);
  uint2* stgP = (uint2*)(region + (size_t)3*256*8704*8);
  uint2* stgQ = (uint2*)(region + (size_t)3*256*8704*8 + (size_t)256*1536*8);
  unsigned* bemb = (unsigned*)region;
  unsigned* bue  = (unsigned*)(region + (size_t)N_NODE*EMB*2);
  unsigned* bpe  = (unsigned*)(region + (size_t)(N_NODE+N_USER)*EMB*2);
  unsigned* vp_bf = (unsigned*)(region + (size_t)37*1024*1024);
  int2*  adjE = (int2*)alloc(((size_t)E_VV+16)*8);
  int2*  vuE  = (int2*)alloc(((size_t)E_VU+16)*8);
  int2*  uvE  = (int2*)alloc(((size_t)E_UV+16)*8);
  int2*  vpE  = (int2*)alloc(((size_t)E_VP+16)*8);
  int2*  pvE  = (int2*)alloc(((size_t)E_VP+16)*8);
  unsigned* eitem_bf = (unsigned*)alloc((size_t)N_USER*64*4);
  unsigned* uvp_bf   = (unsigned*)alloc((size_t)N_USER*64*4);
  float* pv_num   = (float*)alloc((size_t)N_PRICE*EMB*4);
  float* pv_den   = (float*)alloc(N_PRICE*4);

  // 1) weight prep + zero fill + zero sentinels
  k_prep<<<321,256,0,stream>>>(W_aogi, W_bgi1, W_user, Wc_item, Wu_bf,
                               fill, adjE, vuE, uvE, vpE, pvE);

  // 2) Pass A: LDS counting-sort bucket, bursty flush
  k_bucket_all<<<BKT,256,0,stream>>>(
      adj_r,adj_c,adj_v, vu_r,vu_c,vu_v, uv_r,uv_c,uv_v, vp_r,vp_c,vp_v, pv_r,pv_c,pv_v,
      fill, stgA, stgU, stgV, stgP, stgQ);

  // 3) Pass B: CSR finalize via LDS stage (no sort), coalesced flush
  k_csr_all<<<CBT,256,0,stream>>>(stgA, stgU, stgV, stgP, stgQ, fill,
      aS, uS, vS, pS, qS, adjE, vuE, uvE, vpE, pvE);

  // 4) bf16 table conversion (overlays dead staging)
  k_cvt_all<<<((N_NODE+N_USER+N_PRICE)*EMB/4+255)/256,256,0,stream>>>(
      (const float4*)emb, (const float4*)ue, (const float4*)pe,
      (uint2*)bemb, (uint2*)bue, (uint2*)bpe);

  // 5) all row-owned SpMMs in one launch (pv blocks first)
  k_rows_all<<<RBT,256,0,stream>>>(
      (const uint4*)bemb, (const uint4*)bue, (const uint4*)bpe,
      aS, adjE, uS, vuE, pS, vpE, vS, uvE, qS, pvE,
      ipi, mat_vu, mat_uv, lam,
      (float4*)out_item, (uint4*)vp_bf, (uint4*)eitem_bf, (uint4*)uvp_bf,
      pv_num, pv_den);

  // 6) all finals in one launch
  k_finals_all<<<FBT,256,0,stream>>>(
      (const ushort*)bemb, (const ushort*)vp_bf, Wc_item, b_aogi, b_bgi1, out_item,
      (const ushort*)bue, (const ushort*)eitem_bf, (const ushort*)uvp_bf, Wu_bf, b_user, out_user,
      pe, pv_num, pv_den, mat_pv, W_aogp, b_aogp, W_bgp1, b_bgp1, out_price);
}

// Round 13
// 511.143 us; speedup vs baseline: 1.4097x; 1.0625x over previous
//
#include <hip/hip_runtime.h>
#include <hip/hip_bf16.h>

#define N_NODE 100000
#define N_USER 40000
#define N_PRICE 100
#define EMB 128
#define E_VV 2000000
#define E_VP 200000
#define E_VU 2000000
#define E_UV 2000000

#define FOFF0 0
#define FOFF1 256
#define FOFF2 512
#define FOFF3 767
#define FOFF4 1023
#define FTOT  1073
#define EPB   8192
// front kernel block ranges: bucket | cvt | weight-prep
#define BK1 245
#define BK2 490
#define BK3 735
#define BK4 760
#define BKT 785
#define NCVT 17513
#define FR_CVT (BKT + NCVT)
#define FR_TOT (FR_CVT + 320)
// csr
#define CB1 256
#define CB2 512
#define CB3 767
#define CB4 1023
#define CBT 1073
// rows
#define RB_PV   100
#define RB_ITEM 25000
#define RB_USER 10000
#define RBT (RB_PV + RB_ITEM + RB_USER)
// finals
#define FB_ITEM 782
#define FB_USER 313
#define FBT (FB_ITEM + FB_USER + 50)

typedef __attribute__((ext_vector_type(8))) short short8;
typedef __attribute__((ext_vector_type(4))) float f32x4;

__device__ __forceinline__ float sigf(float x){ return 1.f/(1.f+__expf(-x)); }
__device__ __forceinline__ unsigned bfr(float f){
  unsigned u = __float_as_uint(f);
  return (u + 0x7FFFu + ((u>>16)&1u)) >> 16;
}
__device__ __forceinline__ float bf_lo(unsigned u){ return __uint_as_float(u << 16); }
__device__ __forceinline__ float bf_hi(unsigned u){ return __uint_as_float(u & 0xFFFF0000u); }
__device__ __forceinline__ unsigned pack2(float x, float y){ return bfr(x) | (bfr(y)<<16); }

// ---------------- Pass A body: LDS counting-sort bucket, bursty coalesced flush ----------------
template<int E, int RPB, int NB, int CAPc>
__device__ __forceinline__ void bucket_body(int blk,
    const int* __restrict__ rows, const int* __restrict__ cols, const float* __restrict__ vals,
    int* __restrict__ fill, uint2* __restrict__ stg,
    int* cnt, int* gbase, int* lbase, uint2* stage)
{
  const int t = threadIdx.x;
  const int e0 = blk * EPB;
  for (int i = t; i < NB; i += 256) cnt[i] = 0;
  __syncthreads();
  #pragma unroll 4
  for (int i = 0; i < 32; ++i){
    int e = e0 + i*256 + t;
    if (e < E) atomicAdd(&cnt[rows[e]/RPB], 1);
  }
  __syncthreads();
  if (t < 64){   // exclusive scan cnt -> lbase
    int run = 0;
    for (int c0 = 0; c0 < NB; c0 += 64){
      int j = c0 + t;
      int x = (j < NB) ? cnt[j] : 0;
      int s = x;
      #pragma unroll
      for (int d = 1; d < 64; d <<= 1){ int y = __shfl_up(s, d); if (t >= d) s += y; }
      if (j < NB) lbase[j] = run + s - x;
      run += __shfl(s, 63);
    }
  }
  __syncthreads();
  for (int b = t; b < NB; b += 256){
    int c = cnt[b];
    gbase[b] = (c > 0) ? atomicAdd(&fill[b], c) : 0;
    cnt[b] = lbase[b];        // becomes local cursor
  }
  __syncthreads();
  #pragma unroll 4
  for (int i = 0; i < 32; ++i){
    int e = e0 + i*256 + t;
    if (e < E){
      int r = rows[e];
      int b = r/RPB, rl = r - b*RPB;
      int pos = atomicAdd(&cnt[b], 1);
      stage[pos] = make_uint2((unsigned)cols[e] | ((unsigned)rl << 17), __float_as_uint(vals[e]));
    }
  }
  __syncthreads();
  const int wid = t >> 6, lane = t & 63;
  for (int b = wid; b < NB; b += 4){
    int lb = lbase[b];
    int n = cnt[b] - lb;
    int gb = gbase[b];
    for (int j = lane; j < n; j += 64){
      int slot = gb + j; if (slot >= CAPc) slot = CAPc - 1;
      stg[(size_t)b*CAPc + slot] = stage[lb + j];
    }
  }
}

// ---------------- front kernel: bucket (all 5 lists) + table cvt + weight prep ----------------
__global__ __launch_bounds__(256) void k_front(
    const int* __restrict__ aR, const int* __restrict__ aC, const float* __restrict__ aV,
    const int* __restrict__ uR, const int* __restrict__ uC, const float* __restrict__ uV,
    const int* __restrict__ vR, const int* __restrict__ vC, const float* __restrict__ vV,
    const int* __restrict__ pR, const int* __restrict__ pC, const float* __restrict__ pV,
    const int* __restrict__ qR, const int* __restrict__ qC, const float* __restrict__ qV,
    int* __restrict__ fill,
    uint2* __restrict__ stgA, uint2* __restrict__ stgU, uint2* __restrict__ stgV,
    uint2* __restrict__ stgP, uint2* __restrict__ stgQ,
    const float4* __restrict__ se, const float4* __restrict__ su, const float4* __restrict__ sp,
    uint2* __restrict__ de, uint2* __restrict__ du, uint2* __restrict__ dp,
    const float* __restrict__ Wa, const float* __restrict__ Wb, const float* __restrict__ Wu,
    ushort* __restrict__ Wc, ushort* __restrict__ Wub)
{
  __shared__ int cnt[256], gbase[256], lbase[256];
  __shared__ uint2 stage[EPB];
  int b = blockIdx.x;
  if (b < BKT){
    if      (b < BK1) bucket_body<E_VV,391,256,8704>(b,      aR,aC,aV, fill+FOFF0, stgA, cnt, gbase, lbase, stage);
    else if (b < BK2) bucket_body<E_VU,391,256,8704>(b-BK1,  uR,uC,uV, fill+FOFF1, stgU, cnt, gbase, lbase, stage);
    else if (b < BK3) bucket_body<E_UV,157,255,8704>(b-BK2,  vR,vC,vV, fill+FOFF2, stgV, cnt, gbase, lbase, stage);
    else if (b < BK4) bucket_body<E_VP,391,256,1536>(b-BK3,  pR,pC,pV, fill+FOFF3, stgP, cnt, gbase, lbase, stage);
    else              bucket_body<E_VP,  2, 50,5120>(b-BK4,  qR,qC,qV, fill+FOFF4, stgQ, cnt, gbase, lbase, stage);
    return;
  }
  if (b < FR_CVT){
    const int nE = N_NODE*EMB/4, nU = N_USER*EMB/4, nP = N_PRICE*EMB/4;
    int i = (b - BKT)*256 + threadIdx.x;
    const float4* src; uint2* dst; int j;
    if (i < nE){ src = se; dst = de; j = i; }
    else if (i < nE+nU){ src = su; dst = du; j = i-nE; }
    else if (i < nE+nU+nP){ src = sp; dst = dp; j = i-nE-nU; }
    else return;
    float4 v = src[j];
    dst[j] = make_uint2(bfr(v.x) | (bfr(v.y)<<16), bfr(v.z) | (bfr(v.w)<<16));
    return;
  }
  int idx = (b - FR_CVT)*256 + threadIdx.x;
  if (idx < 128*256){
    int n = idx >> 8, k = idx & 255;
    float v = Wa[n*256+k] + ((k < 128) ? Wb[n*128+k] : 0.f);
    Wc[idx] = (ushort)bfr(v);
  } else {
    int j = idx - 128*256;
    if (j < 128*384) Wub[j] = (ushort)bfr(Wu[j]);
  }
}

// ---------------- Pass B: CSR finalize via LDS stage, coalesced flush ----------------
template<int NROW, int RPB, int NB, int CAPc>
__device__ __forceinline__ void csr_body(int b,
    const uint2* __restrict__ stg, const int* __restrict__ fill,
    int* __restrict__ start, int2* __restrict__ csr,
    int* cnt, uint2* stage, int* sbase)
{
  const int t = threadIdx.x;
  const int row0 = b * RPB;
  int R = NROW - row0; if (R > RPB) R = RPB;
  int count = fill[b]; if (count > CAPc) count = CAPc;
  for (int i = t; i < R; i += 256) cnt[i] = 0;
  if (t < 64){
    int run = 0;
    for (int c0 = 0; c0 < NB; c0 += 64){
      int j = c0 + t;
      int x = (j < NB) ? fill[j] : 0;
      int s = x;
      #pragma unroll
      for (int d = 1; d < 64; d <<= 1){ int y = __shfl_up(s, d); if (t >= d) s += y; }
      if (j == b) *sbase = run + s - x;
      run += __shfl(s, 63);
    }
  }
  __syncthreads();
  const int base = *sbase;
  const uint2* mystg = stg + (size_t)b*CAPc;
  for (int j = t; j < count; j += 256)
    atomicAdd(&cnt[mystg[j].x >> 17], 1);
  __syncthreads();
  if (t < 64){
    int run = 0;
    for (int c0 = 0; c0 < R; c0 += 64){
      int i = c0 + t;
      int x = (i < R) ? cnt[i] : 0;
      int s = x;
      #pragma unroll
      for (int d = 1; d < 64; d <<= 1){ int y = __shfl_up(s, d); if (t >= d) s += y; }
      if (i < R) cnt[i] = run + s - x;
      run += __shfl(s, 63);
    }
  }
  __syncthreads();
  for (int i = t; i < R; i += 256) start[row0 + i] = base + cnt[i];
  if (b == NB-1 && t == 0) start[NROW] = base + count;
  __syncthreads();
  for (int j = t; j < count; j += 256){
    uint2 kv = mystg[j];
    int rl = kv.x >> 17;
    int pos = atomicAdd(&cnt[rl], 1);
    stage[pos] = kv;
  }
  __syncthreads();
  for (int j = t; j < count; j += 256){
    uint2 kv = stage[j];
    csr[base + j] = make_int2((int)(kv.x & 0x1FFFF), (int)kv.y);
  }
}

__global__ __launch_bounds__(256) void k_csr_all(
    const uint2* __restrict__ stgA, const uint2* __restrict__ stgU, const uint2* __restrict__ stgV,
    const uint2* __restrict__ stgP, const uint2* __restrict__ stgQ,
    const int* __restrict__ fill,
    int* __restrict__ aS, int* __restrict__ uS, int* __restrict__ vS,
    int* __restrict__ pS, int* __restrict__ qS,
    int2* __restrict__ aE, int2* __restrict__ uE, int2* __restrict__ vE,
    int2* __restrict__ pE, int2* __restrict__ qE)
{
  __shared__ int cnt[391];
  __shared__ int sbase;
  __shared__ uint2 stage[8704];
  int b = blockIdx.x;
  if      (b < CB1) csr_body<N_NODE,391,256,8704>(b,     stgA, fill+FOFF0, aS, aE, cnt, stage, &sbase);
  else if (b < CB2) csr_body<N_NODE,391,256,8704>(b-CB1, stgU, fill+FOFF1, uS, uE, cnt, stage, &sbase);
  else if (b < CB3) csr_body<N_USER,157,255,8704>(b-CB2, stgV, fill+FOFF2, vS, vE, cnt, stage, &sbase);
  else if (b < CB4) csr_body<N_NODE,391,256,1536>(b-CB3, stgP, fill+FOFF3, pS, pE, cnt, stage, &sbase);
  else              csr_body<N_PRICE,  2, 50,5120>(b-CB4, stgQ, fill+FOFF4, qS, qE, cnt, stage, &sbase);
}

// ======== row SpMMs: 16 lanes/edge, uint4 gathers, clamped overrun cols ========

#define FMA8(ACC, U, V)                                     \
  ACC[0] += (V)*bf_lo((U).x); ACC[1] += (V)*bf_hi((U).x);   \
  ACC[2] += (V)*bf_lo((U).y); ACC[3] += (V)*bf_hi((U).y);   \
  ACC[4] += (V)*bf_lo((U).z); ACC[5] += (V)*bf_hi((U).z);   \
  ACC[6] += (V)*bf_lo((U).w); ACC[7] += (V)*bf_hi((U).w);

#define RED8(ACC)                                           \
  _Pragma("unroll")                                         \
  for (int j = 0; j < 8; ++j){                              \
    ACC[j] += __shfl_xor(ACC[j], 16);                       \
    ACC[j] += __shfl_xor(ACC[j], 32);                       \
  }

__device__ __forceinline__ void item_body(int rb,
    const uint4* __restrict__ be4, const uint4* __restrict__ bu4, const uint4* __restrict__ bp4,
    const int* __restrict__ aS, const int2* __restrict__ aE,
    const int* __restrict__ uS, const int2* __restrict__ uE,
    const int* __restrict__ pS, const int2* __restrict__ pE,
    const float* __restrict__ mat_vu, const float* __restrict__ lam,
    float4* __restrict__ out4, uint4* __restrict__ vp4)
{
  const int r = rb*4 + (threadIdx.x >> 6);
  const int l = threadIdx.x & 63;
  const int g = l >> 4, q = l & 15;
  float aA[8] = {}, aU[8] = {}, aP[8] = {};
  float den = 0.f;
  int s = aS[r], e = aS[r+1];
  for (int i = s; i < e; i += 16){
    int2 cv[4]; uint4 u[4];
    #pragma unroll
    for (int k = 0; k < 4; ++k) cv[k] = aE[i + 4*k + g];   // overrun reads clamped below
    #pragma unroll
    for (int k = 0; k < 4; ++k) u[k] = be4[(size_t)(cv[k].x & 0x1FFFF)*16 + q];
    #pragma unroll
    for (int k = 0; k < 4; ++k){
      float v = (i + 4*k + g < e) ? __int_as_float(cv[k].y) : 0.f;
      FMA8(aA, u[k], v)
    }
  }
  s = uS[r]; e = uS[r+1];
  for (int i = s; i < e; i += 16){
    int2 cv[4]; uint4 u[4];
    #pragma unroll
    for (int k = 0; k < 4; ++k) cv[k] = uE[i + 4*k + g];
    #pragma unroll
    for (int k = 0; k < 4; ++k) u[k] = bu4[(size_t)(cv[k].x & 0x1FFFF)*16 + q];
    #pragma unroll
    for (int k = 0; k < 4; ++k){
      float v = (i + 4*k + g < e) ? __int_as_float(cv[k].y) : 0.f;
      FMA8(aU, u[k], v)
      den += v;
    }
  }
  s = pS[r]; e = pS[r+1];
  for (int i = s; i < e; i += 16){
    int2 cv[4]; uint4 u[4];
    #pragma unroll
    for (int k = 0; k < 4; ++k) cv[k] = pE[i + 4*k + g];
    #pragma unroll
    for (int k = 0; k < 4; ++k) u[k] = bp4[(size_t)(cv[k].x & 0x1FFFF)*16 + q];
    #pragma unroll
    for (int k = 0; k < 4; ++k){
      float v = (i + 4*k + g < e) ? __int_as_float(cv[k].y) : 0.f;
      FMA8(aP, u[k], v)
    }
  }
  RED8(aA) RED8(aU) RED8(aP)
  den += __shfl_xor(den, 16); den += __shfl_xor(den, 32);
  float sc = lam[0]*mat_vu[r]/(den + 1e-8f);
  if (g == 0){
    out4[(size_t)r*32 + q*2]     = make_float4(aA[0]+sc*aU[0], aA[1]+sc*aU[1], aA[2]+sc*aU[2], aA[3]+sc*aU[3]);
    out4[(size_t)r*32 + q*2 + 1] = make_float4(aA[4]+sc*aU[4], aA[5]+sc*aU[5], aA[6]+sc*aU[6], aA[7]+sc*aU[7]);
    vp4[(size_t)r*16 + q] = make_uint4(pack2(aP[0],aP[1]), pack2(aP[2],aP[3]), pack2(aP[4],aP[5]), pack2(aP[6],aP[7]));
  }
}

__device__ __forceinline__ void user_body(int rb,
    const uint4* __restrict__ be4, const uint4* __restrict__ bp4,
    const int* __restrict__ S, const int2* __restrict__ E,
    const int* __restrict__ ipi, const float* __restrict__ mat_uv,
    uint4* __restrict__ eit4, uint4* __restrict__ uvp4)
{
  const int r = rb*4 + (threadIdx.x >> 6);
  const int l = threadIdx.x & 63;
  const int g = l >> 4, q = l & 15;
  float aI[8] = {}, aP[8] = {};
  float den = 0.f;
  int s = S[r], e = S[r+1];
  for (int i = s; i < e; i += 8){
    int2 cv[2];
    #pragma unroll
    for (int k = 0; k < 2; ++k) cv[k] = E[i + 4*k + g];
    uint4 u[2]; int ip[2];
    #pragma unroll
    for (int k = 0; k < 2; ++k){
      int c = cv[k].x & 0x1FFFF;
      u[k] = be4[(size_t)c*16 + q];
      ip[k] = ipi[c < N_NODE ? c : N_NODE-1];
    }
    uint4 y[2];
    #pragma unroll
    for (int k = 0; k < 2; ++k) y[k] = bp4[(size_t)ip[k]*16 + q];
    #pragma unroll
    for (int k = 0; k < 2; ++k){
      float v = (i + 4*k + g < e) ? __int_as_float(cv[k].y) : 0.f;
      FMA8(aI, u[k], v)
      FMA8(aP, y[k], v)
      den += v;
    }
  }
  RED8(aI) RED8(aP)
  den += __shfl_xor(den, 16); den += __shfl_xor(den, 32);
  float sc = mat_uv[r]/(den + 1e-8f);
  if (g == 0){
    eit4[(size_t)r*16 + q] = make_uint4(pack2(sc*aI[0],sc*aI[1]), pack2(sc*aI[2],sc*aI[3]),
                                        pack2(sc*aI[4],sc*aI[5]), pack2(sc*aI[6],sc*aI[7]));
    uvp4[(size_t)r*16 + q] = make_uint4(pack2(aP[0],aP[1]), pack2(aP[2],aP[3]),
                                        pack2(aP[4],aP[5]), pack2(aP[6],aP[7]));
  }
}

__device__ __forceinline__ void pv_body(int r,
    const uint4* __restrict__ be4, const int2* __restrict__ E, const int* __restrict__ S,
    float* __restrict__ num, float* __restrict__ den_out)
{
  const int t = threadIdx.x;
  const int wid = t >> 6, l = t & 63;
  const int g = l >> 4, q = l & 15;
  float aP[8] = {}; float den = 0.f;
  int s = S[r], e = S[r+1];
  for (int i0 = s + wid*16; i0 < e; i0 += 64){
    int2 cv[4]; uint4 u[4];
    #pragma unroll
    for (int k = 0; k < 4; ++k) cv[k] = E[i0 + 4*k + g];
    #pragma unroll
    for (int k = 0; k < 4; ++k) u[k] = be4[(size_t)(cv[k].x & 0x1FFFF)*16 + q];
    #pragma unroll
    for (int k = 0; k < 4; ++k){
      float v = (i0 + 4*k + g < e) ? __int_as_float(cv[k].y) : 0.f;
      FMA8(aP, u[k], v)
      den += v;
    }
  }
  RED8(aP)
  den += __shfl_xor(den, 16); den += __shfl_xor(den, 32);
  __shared__ float red[4][16][8];
  __shared__ float dred[4];
  if (g == 0){
    #pragma unroll
    for (int j = 0; j < 8; ++j) red[wid][q][j] = aP[j];
    if (l == 0) dred[wid] = den;
  }
  __syncthreads();
  if (t < 16){
    #pragma unroll
    for (int j = 0; j < 8; ++j)
      num[r*128 + t*8 + j] = red[0][t][j] + red[1][t][j] + red[2][t][j] + red[3][t][j];
    if (t == 0) den_out[r] = dred[0] + dred[1] + dred[2] + dred[3];
  }
}

__global__ __launch_bounds__(256) void k_rows_all(
    const uint4* __restrict__ be4, const uint4* __restrict__ bu4, const uint4* __restrict__ bp4,
    const int* __restrict__ aS, const int2* __restrict__ aE,
    const int* __restrict__ uS, const int2* __restrict__ uE,
    const int* __restrict__ pS, const int2* __restrict__ pE,
    const int* __restrict__ vS, const int2* __restrict__ vE,
    const int* __restrict__ qS, const int2* __restrict__ qE,
    const int* __restrict__ ipi,
    const float* __restrict__ mat_vu, const float* __restrict__ mat_uv, const float* __restrict__ lam,
    float4* __restrict__ out4, uint4* __restrict__ vp4,
    uint4* __restrict__ eit4, uint4* __restrict__ uvp4,
    float* __restrict__ pv_num, float* __restrict__ pv_den)
{
  int b = blockIdx.x;
  if (b < RB_PV){ pv_body(b, be4, qE, qS, pv_num, pv_den); return; }
  b -= RB_PV;
  if (b < RB_ITEM){ item_body(b, be4, bu4, bp4, aS, aE, uS, uE, pS, pE, mat_vu, lam, out4, vp4); return; }
  b -= RB_ITEM;
  user_body(b, be4, bp4, vS, vE, ipi, mat_uv, eit4, uvp4);
}

// ======== finals (epilogues read bf16 tables) ========
__device__ __forceinline__ void item_final_body(int blk, ushort* As, ushort* Bs,
    const ushort* __restrict__ A0, const ushort* __restrict__ A1,
    const ushort* __restrict__ W,
    const float* __restrict__ ba, const float* __restrict__ bb,
    float* __restrict__ out)
{
  const int t = threadIdx.x;
  const int l = t & 63, wv = t >> 6;
  const int wr = (wv>>1)*64, wc = (wv&1)*64;
  const int row0 = blk*128;
  const int lr16 = t >> 3;
  const int slot = t & 7;
  f32x4 acc[4][4] = {};
  for (int s = 0; s < 4; ++s){
    if (s) __syncthreads();
    const int k0 = s*64;
    const ushort* srcA = (k0 < 128) ? (A0 + k0) : (A1 + (k0 - 128));
    #pragma unroll
    for (int i = 0; i < 4; ++i){
      int r = i*32 + lr16;
      int gr = row0 + r; if (gr >= N_NODE) gr = N_NODE-1;
      uint4 va = *(const uint4*)(srcA + (size_t)gr*128 + slot*8);
      *(uint4*)&As[r*64 + ((slot*8) ^ ((r&7)*8))] = va;
      uint4 vb = *(const uint4*)(W + r*256 + k0 + slot*8);
      *(uint4*)&Bs[r*64 + ((slot*8) ^ ((r&7)*8))] = vb;
    }
    __syncthreads();
    #pragma unroll
    for (int kk = 0; kk < 64; kk += 32){
      short8 af[4], bf[4];
      #pragma unroll
      for (int f = 0; f < 4; ++f){
        int ar = wr + f*16 + (l&15);
        af[f] = *(const short8*)&As[ar*64 + ((kk + (l>>4)*8) ^ ((ar&7)*8))];
        int bn = wc + f*16 + (l&15);
        bf[f] = *(const short8*)&Bs[bn*64 + ((kk + (l>>4)*8) ^ ((bn&7)*8))];
      }
      #pragma unroll
      for (int fi = 0; fi < 4; ++fi)
        #pragma unroll
        for (int fj = 0; fj < 4; ++fj)
          acc[fi][fj] = __builtin_amdgcn_mfma_f32_16x16x32_bf16(af[fi], bf[fj], acc[fi][fj], 0, 0, 0);
    }
  }
  const int g4 = (l>>4)*4;
  #pragma unroll
  for (int fi = 0; fi < 4; ++fi){
    #pragma unroll
    for (int r = 0; r < 4; ++r){
      int grow = row0 + wr + fi*16 + g4 + r;
      if (grow < N_NODE){
        #pragma unroll
        for (int fj = 0; fj < 4; ++fj){
          int col = wc + fj*16 + (l&15);
          float x = acc[fi][fj][r] + ba[col] + bb[col];
          unsigned pv2 = *(const unsigned*)&A1[(size_t)grow*128 + (col & ~1)];
          float v = (col & 1) ? bf_hi(pv2) : bf_lo(pv2);
          unsigned em2 = *(const unsigned*)&A0[(size_t)grow*128 + (col & ~1)];
          float em = (col & 1) ? bf_hi(em2) : bf_lo(em2);
          size_t o = (size_t)grow*128 + col;
          out[o] = em + sigf(x)*v + out[o];
        }
      }
    }
  }
}

__device__ __forceinline__ void user_final_body(int blk, ushort* As, ushort* Bs,
    const ushort* __restrict__ A0, const ushort* __restrict__ A1, const ushort* __restrict__ A2,
    const ushort* __restrict__ W,
    const float* __restrict__ bu,
    float* __restrict__ out)
{
  const int t = threadIdx.x;
  const int l = t & 63, wv = t >> 6;
  const int wr = (wv>>1)*64, wc = (wv&1)*64;
  const int row0 = blk*128;
  const int lr16 = t >> 3;
  const int slot = t & 7;
  f32x4 acc[4][4] = {};
  for (int s = 0; s < 6; ++s){
    if (s) __syncthreads();
    const int k0 = s*64;
    const ushort* base = (s < 2) ? A0 : ((s < 4) ? A1 : A2);
    const ushort* srcA = base + (s & 1)*64;
    #pragma unroll
    for (int i = 0; i < 4; ++i){
      int r = i*32 + lr16;
      int gr = row0 + r; if (gr >= N_USER) gr = N_USER-1;
      uint4 va = *(const uint4*)(srcA + (size_t)gr*128 + slot*8);
      *(uint4*)&As[r*64 + ((slot*8) ^ ((r&7)*8))] = va;
      uint4 vb = *(const uint4*)(W + r*384 + k0 + slot*8);
      *(uint4*)&Bs[r*64 + ((slot*8) ^ ((r&7)*8))] = vb;
    }
    __syncthreads();
    #pragma unroll
    for (int kk = 0; kk < 64; kk += 32){
      short8 af[4], bf[4];
      #pragma unroll
      for (int f = 0; f < 4; ++f){
        int ar = wr + f*16 + (l&15);
        af[f] = *(const short8*)&As[ar*64 + ((kk + (l>>4)*8) ^ ((ar&7)*8))];
        int bn = wc + f*16 + (l&15);
        bf[f] = *(const short8*)&Bs[bn*64 + ((kk + (l>>4)*8) ^ ((bn&7)*8))];
      }
      #pragma unroll
      for (int fi = 0; fi < 4; ++fi)
        #pragma unroll
        for (int fj = 0; fj < 4; ++fj)
          acc[fi][fj] = __builtin_amdgcn_mfma_f32_16x16x32_bf16(af[fi], bf[fj], acc[fi][fj], 0, 0, 0);
    }
  }
  const int g4 = (l>>4)*4;
  #pragma unroll
  for (int fi = 0; fi < 4; ++fi){
    #pragma unroll
    for (int r = 0; r < 4; ++r){
      int grow = row0 + wr + fi*16 + g4 + r;
      if (grow < N_USER){
        #pragma unroll
        for (int fj = 0; fj < 4; ++fj){
          int col = wc + fj*16 + (l&15);
          float g = sigf(acc[fi][fj][r] + bu[col]);
          unsigned e2 = *(const unsigned*)&A1[(size_t)grow*128 + (col & ~1)];
          float ei = (col & 1) ? bf_hi(e2) : bf_lo(e2);
          unsigned u2 = *(const unsigned*)&A0[(size_t)grow*128 + (col & ~1)];
          float uu = (col & 1) ? bf_hi(u2) : bf_lo(u2);
          size_t o = (size_t)grow*128 + col;
          out[o] = g*uu + (1.f - g)*ei;
        }
      }
    }
  }
}

__device__ __forceinline__ void price_final_body(int blk, float* A2,
    const float* __restrict__ pe, const float* __restrict__ num, const float* __restrict__ den,
    const float* __restrict__ mat_pv,
    const float* __restrict__ Wa, const float* __restrict__ ba,
    const float* __restrict__ Wb, const float* __restrict__ bb,
    float* __restrict__ out_price)
{
  int t = threadIdx.x;
  #pragma unroll
  for (int i = 0; i < 2; ++i){
    int flat = i*256 + t;
    int rl = flat >> 8; int k = flat & 255;
    int r = blk*2 + rl;
    float v;
    if (k < 128) v = pe[r*128 + k];
    else         v = num[r*128 + (k-128)] / (den[r] + 1e-8f) * mat_pv[r];
    A2[rl*256 + k] = v;
  }
  __syncthreads();
  int rl = t >> 7; int c = t & 127;
  int r = blk*2 + rl;
  float x = 0.f;
  #pragma unroll 4
  for (int k = 0; k < 256; ++k){
    float w = (k < 128) ? (Wa[c*256 + k] + Wb[c*128 + k]) : Wa[c*256 + k];
    x += A2[rl*256 + k]*w;
  }
  float g = sigf(x + ba[c] + bb[c]);
  out_price[r*128 + c] = pe[r*128 + c] + g*A2[rl*256 + 128 + c];
}

__global__ __launch_bounds__(256) void k_finals_all(
    const ushort* __restrict__ bemb, const ushort* __restrict__ vp_bf, const ushort* __restrict__ Wc,
    const float* __restrict__ b_aogi, const float* __restrict__ b_bgi1,
    float* __restrict__ out_item,
    const ushort* __restrict__ bue, const ushort* __restrict__ eitem_bf, const ushort* __restrict__ uvp_bf,
    const ushort* __restrict__ Wub, const float* __restrict__ b_user,
    float* __restrict__ out_user,
    const float* __restrict__ pe, const float* __restrict__ pv_num, const float* __restrict__ pv_den,
    const float* __restrict__ mat_pv,
    const float* __restrict__ W_aogp, const float* __restrict__ b_aogp,
    const float* __restrict__ W_bgp1, const float* __restrict__ b_bgp1,
    float* __restrict__ out_price)
{
  __shared__ __align__(16) ushort As[128*64];
  __shared__ __align__(16) ushort Bs[128*64];
  __shared__ float A2[512];
  int b = blockIdx.x;
  if (b < FB_ITEM){
    item_final_body(b, As, Bs, bemb, vp_bf, Wc, b_aogi, b_bgi1, out_item);
  } else if (b < FB_ITEM + FB_USER){
    user_final_body(b - FB_ITEM, As, Bs, bue, eitem_bf, uvp_bf, Wub, b_user, out_user);
  } else {
    price_final_body(b - FB_ITEM - FB_USER, A2, pe, pv_num, pv_den, mat_pv,
                     W_aogp, b_aogp, W_bgp1, b_bgp1, out_price);
  }
}

extern "C" void kernel_launch(void* const* d_in, const int* in_sizes, int n_in,
                              void* d_out, int out_size, void* d_ws, size_t ws_size,
                              hipStream_t stream){
  (void)in_sizes; (void)n_in; (void)out_size; (void)ws_size;
  const float* emb = (const float*)d_in[0];
  const float* pe  = (const float*)d_in[1];
  const float* ue  = (const float*)d_in[2];
  const int*   adj_r = (const int*)d_in[3];  const int* adj_c = (const int*)d_in[4];  const float* adj_v = (const float*)d_in[5];
  const int*   vp_r  = (const int*)d_in[6];  const int* vp_c  = (const int*)d_in[7];  const float* vp_v  = (const float*)d_in[8];
  const int*   vu_r  = (const int*)d_in[9];  const int* vu_c  = (const int*)d_in[10]; const float* vu_v  = (const float*)d_in[11];
  const int*   pv_r  = (const int*)d_in[12]; const int* pv_c  = (const int*)d_in[13]; const float* pv_v  = (const float*)d_in[14];
  const int*   uv_r  = (const int*)d_in[15]; const int* uv_c  = (const int*)d_in[16]; const float* uv_v  = (const float*)d_in[17];
  const int*   ipi   = (const int*)d_in[18];
  const float* mat_vu = (const float*)d_in[19];
  const float* mat_pv = (const float*)d_in[20];
  const float* mat_uv = (const float*)d_in[21];
  const float* W_aogi = (const float*)d_in[22]; const float* b_aogi = (const float*)d_in[23];
  const float* W_bgi1 = (const float*)d_in[24]; const float* b_bgi1 = (const float*)d_in[25];
  const float* W_aogp = (const float*)d_in[26]; const float* b_aogp = (const float*)d_in[27];
  const float* W_bgp1 = (const float*)d_in[28]; const float* b_bgp1 = (const float*)d_in[29];
  const float* W_user = (const float*)d_in[30]; const float* b_user = (const float*)d_in[31];
  const float* lam    = (const float*)d_in[32];

  float* out_item  = (float*)d_out;
  float* out_price = out_item + (size_t)N_NODE*EMB;
  float* out_user  = out_price + (size_t)N_PRICE*EMB;

  // edge staging lives in d_out (dead until k_rows_all/k_finals_all rewrite it)
  char* ob = (char*)d_out;
  const size_t SEGBIG = (size_t)256*8704*8;   // 17,825,792 B
  uint2* stgA = (uint2*)ob;
  uint2* stgU = (uint2*)(ob + SEGBIG);
  uint2* stgV = (uint2*)(ob + 2*SEGBIG);
  uint2* stgP = (uint2*)(ob + 3*SEGBIG);
  uint2* stgQ = (uint2*)(ob + 3*SEGBIG + (size_t)256*1536*8);   // ends ~58.7MB < 71.7MB

  char* w = (char*)d_ws;
  size_t off = 0;
  auto alloc = [&](size_t bytes)->char*{
    char* p = w + off;
    off = (off + bytes + 255) & ~(size_t)255;
    return p;
  };
  int* fill = (int*)alloc(FTOT*4);
  int* aS  = (int*)alloc((N_NODE+1)*4);
  int* uS  = (int*)alloc((N_NODE+1)*4);
  int* vS  = (int*)alloc((N_USER+1)*4);
  int* pS  = (int*)alloc((N_NODE+1)*4);
  int* qS  = (int*)alloc(101*4);
  ushort* Wc_item = (ushort*)alloc(128*256*2);
  ushort* Wu_bf   = (ushort*)alloc(128*384*2);
  // bf16 tables + vp_bf (no longer overlaid with staging)
  char* region = alloc((size_t)62*1024*1024);
  unsigned* bemb = (unsigned*)region;                                    // 25.6MB
  unsigned* bue  = (unsigned*)(region + (size_t)N_NODE*EMB*2);           // 10.24MB
  unsigned* bpe  = (unsigned*)(region + (size_t)(N_NODE+N_USER)*EMB*2);  // 25.6KB
  unsigned* vp_bf = (unsigned*)(region + (size_t)(N_NODE+N_USER+N_PRICE)*EMB*2); // 25.6MB
  int2*  adjE = (int2*)alloc(((size_t)E_VV+16)*8);
  int2*  vuE  = (int2*)alloc(((size_t)E_VU+16)*8);
  int2*  uvE  = (int2*)alloc(((size_t)E_UV+16)*8);
  int2*  vpE  = (int2*)alloc(((size_t)E_VP+16)*8);
  int2*  pvE  = (int2*)alloc(((size_t)E_VP+16)*8);
  unsigned* eitem_bf = (unsigned*)alloc((size_t)N_USER*64*4);
  unsigned* uvp_bf   = (unsigned*)alloc((size_t)N_USER*64*4);
  float* pv_num   = (float*)alloc((size_t)N_PRICE*EMB*4);
  float* pv_den   = (float*)alloc(N_PRICE*4);

  // 1) zero bucket fill counters
  hipMemsetAsync(fill, 0, FTOT*4, stream);

  // 2) front: bucket (stg in d_out) + bf16 table cvt + weight prep, one launch
  k_front<<<FR_TOT,256,0,stream>>>(
      adj_r,adj_c,adj_v, vu_r,vu_c,vu_v, uv_r,uv_c,uv_v, vp_r,vp_c,vp_v, pv_r,pv_c,pv_v,
      fill, stgA, stgU, stgV, stgP, stgQ,
      (const float4*)emb, (const float4*)ue, (const float4*)pe,
      (uint2*)bemb, (uint2*)bue, (uint2*)bpe,
      W_aogi, W_bgi1, W_user, Wc_item, Wu_bf);

  // 3) CSR finalize (reads staging from d_out)
  k_csr_all<<<CBT,256,0,stream>>>(stgA, stgU, stgV, stgP, stgQ, fill,
      aS, uS, vS, pS, qS, adjE, vuE, uvE, vpE, pvE);

  // 4) all row-owned SpMMs (out_item overwrites dead staging in d_out)
  k_rows_all<<<RBT,256,0,stream>>>(
      (const uint4*)bemb, (const uint4*)bue, (const uint4*)bpe,
      aS, adjE, uS, vuE, pS, vpE, vS, uvE, qS, pvE,
      ipi, mat_vu, mat_uv, lam,
      (float4*)out_item, (uint4*)vp_bf, (uint4*)eitem_bf, (uint4*)uvp_bf,
      pv_num, pv_den);

  // 5) all finals
  k_finals_all<<<FBT,256,0,stream>>>(
      (const ushort*)bemb, (const ushort*)vp_bf, Wc_item, b_aogi, b_bgi1, out_item,
      (const ushort*)bue, (const ushort*)eitem_bf, (const ushort*)uvp_bf, Wu_bf, b_user, out_user,
      pe, pv_num, pv_den, mat_pv, W_aogp, b_aogp, W_bgp1, b_bgp1, out_price);
}

// Round 14
// 509.842 us; speedup vs baseline: 1.4133x; 1.0026x over previous
//
#include <hip/hip_runtime.h>
#include <hip/hip_bf16.h>

#define N_NODE 100000
#define N_USER 40000
#define N_PRICE 100
#define EMB 128
#define E_VV 2000000
#define E_VP 200000
#define E_VU 2000000
#define E_UV 2000000

#define FOFF0 0
#define FOFF1 256
#define FOFF2 512
#define FOFF3 767
#define FOFF4 1023
#define FTOT  1073
#define EPB   8192
// front kernel: bucket | weight-prep
#define BK1 245
#define BK2 490
#define BK3 735
#define BK4 760
#define BKT 785
#define FR_TOT (BKT + 320)
// csr kernel: csr | cvt
#define CB1 256
#define CB2 512
#define CB3 767
#define CB4 1023
#define CBT 1073
#define NCVT 17513
#define CS_TOT (CBT + NCVT)
// rows
#define RB_PV   100
#define RB_ITEM 25000
#define RB_USER 10000
#define RBT (RB_PV + RB_ITEM + RB_USER)
// finals
#define FB_ITEM 782
#define FB_USER 313
#define FBT (FB_ITEM + FB_USER + 50)

typedef __attribute__((ext_vector_type(8))) short short8;
typedef __attribute__((ext_vector_type(4))) float f32x4;

__device__ __forceinline__ float sigf(float x){ return 1.f/(1.f+__expf(-x)); }
__device__ __forceinline__ unsigned bfr(float f){
  unsigned u = __float_as_uint(f);
  return (u + 0x7FFFu + ((u>>16)&1u)) >> 16;
}
__device__ __forceinline__ float bf_lo(unsigned u){ return __uint_as_float(u << 16); }
__device__ __forceinline__ float bf_hi(unsigned u){ return __uint_as_float(u & 0xFFFF0000u); }
__device__ __forceinline__ unsigned pack2(float x, float y){ return bfr(x) | (bfr(y)<<16); }

// ---------------- Pass A body: LDS counting-sort bucket (register-cached rows), bursty flush ----------------
template<int E, int RPB, int NB, int CAPc>
__device__ __forceinline__ void bucket_body(int blk,
    const int* __restrict__ rows, const int* __restrict__ cols, const float* __restrict__ vals,
    int* __restrict__ fill, uint2* __restrict__ stg,
    int* cnt, int* gbase, int* lbase, uint2* stage)
{
  const int t = threadIdx.x;
  const int e0 = blk * EPB;
  for (int i = t; i < NB; i += 256) cnt[i] = 0;
  __syncthreads();
  int rr[32];
  #pragma unroll 4
  for (int i = 0; i < 32; ++i){
    int e = e0 + i*256 + t;
    rr[i] = (e < E) ? rows[e] : -1;
    if (rr[i] >= 0) atomicAdd(&cnt[rr[i]/RPB], 1);
  }
  __syncthreads();
  if (t < 64){   // exclusive scan cnt -> lbase
    int run = 0;
    for (int c0 = 0; c0 < NB; c0 += 64){
      int j = c0 + t;
      int x = (j < NB) ? cnt[j] : 0;
      int s = x;
      #pragma unroll
      for (int d = 1; d < 64; d <<= 1){ int y = __shfl_up(s, d); if (t >= d) s += y; }
      if (j < NB) lbase[j] = run + s - x;
      run += __shfl(s, 63);
    }
  }
  __syncthreads();
  for (int b = t; b < NB; b += 256){
    int c = cnt[b];
    gbase[b] = (c > 0) ? atomicAdd(&fill[b], c) : 0;
    cnt[b] = lbase[b];        // becomes local cursor
  }
  __syncthreads();
  #pragma unroll 4
  for (int i = 0; i < 32; ++i){
    if (rr[i] >= 0){
      int e = e0 + i*256 + t;
      int b = rr[i]/RPB, rl = rr[i] - b*RPB;
      int pos = atomicAdd(&cnt[b], 1);
      stage[pos] = make_uint2((unsigned)cols[e] | ((unsigned)rl << 17), __float_as_uint(vals[e]));
    }
  }
  __syncthreads();
  const int wid = t >> 6, lane = t & 63;
  for (int b = wid; b < NB; b += 4){
    int lb = lbase[b];
    int n = cnt[b] - lb;
    int gb = gbase[b];
    for (int j = lane; j < n; j += 64){
      int slot = gb + j; if (slot >= CAPc) slot = CAPc - 1;
      stg[(size_t)b*CAPc + slot] = stage[lb + j];
    }
  }
}

// ---------------- front kernel: bucket (all 5 lists) + weight prep ----------------
__global__ __launch_bounds__(256) void k_front(
    const int* __restrict__ aR, const int* __restrict__ aC, const float* __restrict__ aV,
    const int* __restrict__ uR, const int* __restrict__ uC, const float* __restrict__ uV,
    const int* __restrict__ vR, const int* __restrict__ vC, const float* __restrict__ vV,
    const int* __restrict__ pR, const int* __restrict__ pC, const float* __restrict__ pV,
    const int* __restrict__ qR, const int* __restrict__ qC, const float* __restrict__ qV,
    int* __restrict__ fill,
    uint2* __restrict__ stgA, uint2* __restrict__ stgU, uint2* __restrict__ stgV,
    uint2* __restrict__ stgP, uint2* __restrict__ stgQ,
    const float* __restrict__ Wa, const float* __restrict__ Wb, const float* __restrict__ Wu,
    ushort* __restrict__ Wc, ushort* __restrict__ Wub)
{
  __shared__ int cnt[256], gbase[256], lbase[256];
  __shared__ uint2 stage[EPB];
  int b = blockIdx.x;
  if (b < BKT){
    if      (b < BK1) bucket_body<E_VV,391,256,8704>(b,      aR,aC,aV, fill+FOFF0, stgA, cnt, gbase, lbase, stage);
    else if (b < BK2) bucket_body<E_VU,391,256,8704>(b-BK1,  uR,uC,uV, fill+FOFF1, stgU, cnt, gbase, lbase, stage);
    else if (b < BK3) bucket_body<E_UV,157,255,8704>(b-BK2,  vR,vC,vV, fill+FOFF2, stgV, cnt, gbase, lbase, stage);
    else if (b < BK4) bucket_body<E_VP,391,256,1536>(b-BK3,  pR,pC,pV, fill+FOFF3, stgP, cnt, gbase, lbase, stage);
    else              bucket_body<E_VP,  2, 50,5120>(b-BK4,  qR,qC,qV, fill+FOFF4, stgQ, cnt, gbase, lbase, stage);
    return;
  }
  int idx = (b - BKT)*256 + threadIdx.x;
  if (idx < 128*256){
    int n = idx >> 8, k = idx & 255;
    float v = Wa[n*256+k] + ((k < 128) ? Wb[n*128+k] : 0.f);
    Wc[idx] = (ushort)bfr(v);
  } else {
    int j = idx - 128*256;
    if (j < 128*384) Wub[j] = (ushort)bfr(Wu[j]);
  }
}

// ---------------- Pass B body: CSR finalize via LDS stage, coalesced flush ----------------
template<int NROW, int RPB, int NB, int CAPc>
__device__ __forceinline__ void csr_body(int b,
    const uint2* __restrict__ stg, const int* __restrict__ fill,
    int* __restrict__ start, int2* __restrict__ csr,
    int* cnt, uint2* stage, int* sbase)
{
  const int t = threadIdx.x;
  const int row0 = b * RPB;
  int R = NROW - row0; if (R > RPB) R = RPB;
  int count = fill[b]; if (count > CAPc) count = CAPc;
  for (int i = t; i < R; i += 256) cnt[i] = 0;
  if (t < 64){
    int run = 0;
    for (int c0 = 0; c0 < NB; c0 += 64){
      int j = c0 + t;
      int x = (j < NB) ? fill[j] : 0;
      int s = x;
      #pragma unroll
      for (int d = 1; d < 64; d <<= 1){ int y = __shfl_up(s, d); if (t >= d) s += y; }
      if (j == b) *sbase = run + s - x;
      run += __shfl(s, 63);
    }
  }
  __syncthreads();
  const int base = *sbase;
  const uint2* mystg = stg + (size_t)b*CAPc;
  for (int j = t; j < count; j += 256)
    atomicAdd(&cnt[mystg[j].x >> 17], 1);
  __syncthreads();
  if (t < 64){
    int run = 0;
    for (int c0 = 0; c0 < R; c0 += 64){
      int i = c0 + t;
      int x = (i < R) ? cnt[i] : 0;
      int s = x;
      #pragma unroll
      for (int d = 1; d < 64; d <<= 1){ int y = __shfl_up(s, d); if (t >= d) s += y; }
      if (i < R) cnt[i] = run + s - x;
      run += __shfl(s, 63);
    }
  }
  __syncthreads();
  for (int i = t; i < R; i += 256) start[row0 + i] = base + cnt[i];
  if (b == NB-1 && t == 0) start[NROW] = base + count;
  __syncthreads();
  for (int j = t; j < count; j += 256){
    uint2 kv = mystg[j];
    int rl = kv.x >> 17;
    int pos = atomicAdd(&cnt[rl], 1);
    stage[pos] = kv;
  }
  __syncthreads();
  for (int j = t; j < count; j += 256){
    uint2 kv = stage[j];
    csr[base + j] = make_int2((int)(kv.x & 0x1FFFF), (int)kv.y);
  }
}

// ---------------- csr kernel: CSR finalize + bf16 table cvt (fills idle wave slots) ----------------
__global__ __launch_bounds__(256) void k_csr_all(
    const uint2* __restrict__ stgA, const uint2* __restrict__ stgU, const uint2* __restrict__ stgV,
    const uint2* __restrict__ stgP, const uint2* __restrict__ stgQ,
    const int* __restrict__ fill,
    int* __restrict__ aS, int* __restrict__ uS, int* __restrict__ vS,
    int* __restrict__ pS, int* __restrict__ qS,
    int2* __restrict__ aE, int2* __restrict__ uE, int2* __restrict__ vE,
    int2* __restrict__ pE, int2* __restrict__ qE,
    const float4* __restrict__ se, const float4* __restrict__ su, const float4* __restrict__ sp,
    uint2* __restrict__ de, uint2* __restrict__ du, uint2* __restrict__ dp)
{
  int b = blockIdx.x;
  if (b >= CBT){
    const int nE = N_NODE*EMB/4, nU = N_USER*EMB/4, nP = N_PRICE*EMB/4;
    int i = (b - CBT)*256 + threadIdx.x;
    const float4* src; uint2* dst; int j;
    if (i < nE){ src = se; dst = de; j = i; }
    else if (i < nE+nU){ src = su; dst = du; j = i-nE; }
    else if (i < nE+nU+nP){ src = sp; dst = dp; j = i-nE-nU; }
    else return;
    float4 v = src[j];
    dst[j] = make_uint2(bfr(v.x) | (bfr(v.y)<<16), bfr(v.z) | (bfr(v.w)<<16));
    return;
  }
  __shared__ int cnt[391];
  __shared__ int sbase;
  __shared__ uint2 stage[8704];
  if      (b < CB1) csr_body<N_NODE,391,256,8704>(b,     stgA, fill+FOFF0, aS, aE, cnt, stage, &sbase);
  else if (b < CB2) csr_body<N_NODE,391,256,8704>(b-CB1, stgU, fill+FOFF1, uS, uE, cnt, stage, &sbase);
  else if (b < CB3) csr_body<N_USER,157,255,8704>(b-CB2, stgV, fill+FOFF2, vS, vE, cnt, stage, &sbase);
  else if (b < CB4) csr_body<N_NODE,391,256,1536>(b-CB3, stgP, fill+FOFF3, pS, pE, cnt, stage, &sbase);
  else              csr_body<N_PRICE,  2, 50,5120>(b-CB4, stgQ, fill+FOFF4, qS, qE, cnt, stage, &sbase);
}

// ======== row SpMMs: 16 lanes/edge, uint4 gathers, clamped overrun cols ========

#define FMA8(ACC, U, V)                                     \
  ACC[0] += (V)*bf_lo((U).x); ACC[1] += (V)*bf_hi((U).x);   \
  ACC[2] += (V)*bf_lo((U).y); ACC[3] += (V)*bf_hi((U).y);   \
  ACC[4] += (V)*bf_lo((U).z); ACC[5] += (V)*bf_hi((U).z);   \
  ACC[6] += (V)*bf_lo((U).w); ACC[7] += (V)*bf_hi((U).w);

#define RED8(ACC)                                           \
  _Pragma("unroll")                                         \
  for (int j = 0; j < 8; ++j){                              \
    ACC[j] += __shfl_xor(ACC[j], 16);                       \
    ACC[j] += __shfl_xor(ACC[j], 32);                       \
  }

__device__ __forceinline__ void item_body(int rb,
    const uint4* __restrict__ be4, const uint4* __restrict__ bu4, const uint4* __restrict__ bp4,
    const int* __restrict__ aS, const int2* __restrict__ aE,
    const int* __restrict__ uS, const int2* __restrict__ uE,
    const int* __restrict__ pS, const int2* __restrict__ pE,
    const float* __restrict__ mat_vu, const float* __restrict__ lam,
    float4* __restrict__ out4, uint4* __restrict__ vp4)
{
  const int r = rb*4 + (threadIdx.x >> 6);
  const int l = threadIdx.x & 63;
  const int g = l >> 4, q = l & 15;
  float aA[8] = {}, aU[8] = {}, aP[8] = {};
  float den = 0.f;
  int s = aS[r], e = aS[r+1];
  for (int i = s; i < e; i += 16){
    int2 cv[4]; uint4 u[4];
    #pragma unroll
    for (int k = 0; k < 4; ++k) cv[k] = aE[i + 4*k + g];   // overrun reads clamped below
    #pragma unroll
    for (int k = 0; k < 4; ++k) u[k] = be4[(size_t)(cv[k].x & 0x1FFFF)*16 + q];
    #pragma unroll
    for (int k = 0; k < 4; ++k){
      float v = (i + 4*k + g < e) ? __int_as_float(cv[k].y) : 0.f;
      FMA8(aA, u[k], v)
    }
  }
  s = uS[r]; e = uS[r+1];
  for (int i = s; i < e; i += 16){
    int2 cv[4]; uint4 u[4];
    #pragma unroll
    for (int k = 0; k < 4; ++k) cv[k] = uE[i + 4*k + g];
    #pragma unroll
    for (int k = 0; k < 4; ++k) u[k] = bu4[(size_t)(cv[k].x & 0x1FFFF)*16 + q];
    #pragma unroll
    for (int k = 0; k < 4; ++k){
      float v = (i + 4*k + g < e) ? __int_as_float(cv[k].y) : 0.f;
      FMA8(aU, u[k], v)
      den += v;
    }
  }
  s = pS[r]; e = pS[r+1];
  for (int i = s; i < e; i += 16){
    int2 cv[4]; uint4 u[4];
    #pragma unroll
    for (int k = 0; k < 4; ++k) cv[k] = pE[i + 4*k + g];
    #pragma unroll
    for (int k = 0; k < 4; ++k) u[k] = bp4[(size_t)(cv[k].x & 0x1FFFF)*16 + q];
    #pragma unroll
    for (int k = 0; k < 4; ++k){
      float v = (i + 4*k + g < e) ? __int_as_float(cv[k].y) : 0.f;
      FMA8(aP, u[k], v)
    }
  }
  RED8(aA) RED8(aU) RED8(aP)
  den += __shfl_xor(den, 16); den += __shfl_xor(den, 32);
  float sc = lam[0]*mat_vu[r]/(den + 1e-8f);
  if (g == 0){
    out4[(size_t)r*32 + q*2]     = make_float4(aA[0]+sc*aU[0], aA[1]+sc*aU[1], aA[2]+sc*aU[2], aA[3]+sc*aU[3]);
    out4[(size_t)r*32 + q*2 + 1] = make_float4(aA[4]+sc*aU[4], aA[5]+sc*aU[5], aA[6]+sc*aU[6], aA[7]+sc*aU[7]);
    vp4[(size_t)r*16 + q] = make_uint4(pack2(aP[0],aP[1]), pack2(aP[2],aP[3]), pack2(aP[4],aP[5]), pack2(aP[6],aP[7]));
  }
}

__device__ __forceinline__ void user_body(int rb,
    const uint4* __restrict__ be4, const uint4* __restrict__ bp4,
    const int* __restrict__ S, const int2* __restrict__ E,
    const int* __restrict__ ipi, const float* __restrict__ mat_uv,
    uint4* __restrict__ eit4, uint4* __restrict__ uvp4)
{
  const int r = rb*4 + (threadIdx.x >> 6);
  const int l = threadIdx.x & 63;
  const int g = l >> 4, q = l & 15;
  float aI[8] = {}, aP[8] = {};
  float den = 0.f;
  int s = S[r], e = S[r+1];
  for (int i = s; i < e; i += 8){
    int2 cv[2];
    #pragma unroll
    for (int k = 0; k < 2; ++k) cv[k] = E[i + 4*k + g];
    uint4 u[2]; int ip[2];
    #pragma unroll
    for (int k = 0; k < 2; ++k){
      int c = cv[k].x & 0x1FFFF;
      u[k] = be4[(size_t)c*16 + q];
      ip[k] = ipi[c < N_NODE ? c : N_NODE-1];
    }
    uint4 y[2];
    #pragma unroll
    for (int k = 0; k < 2; ++k) y[k] = bp4[(size_t)ip[k]*16 + q];
    #pragma unroll
    for (int k = 0; k < 2; ++k){
      float v = (i + 4*k + g < e) ? __int_as_float(cv[k].y) : 0.f;
      FMA8(aI, u[k], v)
      FMA8(aP, y[k], v)
      den += v;
    }
  }
  RED8(aI) RED8(aP)
  den += __shfl_xor(den, 16); den += __shfl_xor(den, 32);
  float sc = mat_uv[r]/(den + 1e-8f);
  if (g == 0){
    eit4[(size_t)r*16 + q] = make_uint4(pack2(sc*aI[0],sc*aI[1]), pack2(sc*aI[2],sc*aI[3]),
                                        pack2(sc*aI[4],sc*aI[5]), pack2(sc*aI[6],sc*aI[7]));
    uvp4[(size_t)r*16 + q] = make_uint4(pack2(aP[0],aP[1]), pack2(aP[2],aP[3]),
                                        pack2(aP[4],aP[5]), pack2(aP[6],aP[7]));
  }
}

__device__ __forceinline__ void pv_body(int r,
    const uint4* __restrict__ be4, const int2* __restrict__ E, const int* __restrict__ S,
    float* __restrict__ num, float* __restrict__ den_out)
{
  const int t = threadIdx.x;
  const int wid = t >> 6, l = t & 63;
  const int g = l >> 4, q = l & 15;
  float aP[8] = {}; float den = 0.f;
  int s = S[r], e = S[r+1];
  for (int i0 = s + wid*16; i0 < e; i0 += 64){
    int2 cv[4]; uint4 u[4];
    #pragma unroll
    for (int k = 0; k < 4; ++k) cv[k] = E[i0 + 4*k + g];
    #pragma unroll
    for (int k = 0; k < 4; ++k) u[k] = be4[(size_t)(cv[k].x & 0x1FFFF)*16 + q];
    #pragma unroll
    for (int k = 0; k < 4; ++k){
      float v = (i0 + 4*k + g < e) ? __int_as_float(cv[k].y) : 0.f;
      FMA8(aP, u[k], v)
      den += v;
    }
  }
  RED8(aP)
  den += __shfl_xor(den, 16); den += __shfl_xor(den, 32);
  __shared__ float red[4][16][8];
  __shared__ float dred[4];
  if (g == 0){
    #pragma unroll
    for (int j = 0; j < 8; ++j) red[wid][q][j] = aP[j];
    if (l == 0) dred[wid] = den;
  }
  __syncthreads();
  if (t < 16){
    #pragma unroll
    for (int j = 0; j < 8; ++j)
      num[r*128 + t*8 + j] = red[0][t][j] + red[1][t][j] + red[2][t][j] + red[3][t][j];
    if (t == 0) den_out[r] = dred[0] + dred[1] + dred[2] + dred[3];
  }
}

__global__ __launch_bounds__(256) void k_rows_all(
    const uint4* __restrict__ be4, const uint4* __restrict__ bu4, const uint4* __restrict__ bp4,
    const int* __restrict__ aS, const int2* __restrict__ aE,
    const int* __restrict__ uS, const int2* __restrict__ uE,
    const int* __restrict__ pS, const int2* __restrict__ pE,
    const int* __restrict__ vS, const int2* __restrict__ vE,
    const int* __restrict__ qS, const int2* __restrict__ qE,
    const int* __restrict__ ipi,
    const float* __restrict__ mat_vu, const float* __restrict__ mat_uv, const float* __restrict__ lam,
    float4* __restrict__ out4, uint4* __restrict__ vp4,
    uint4* __restrict__ eit4, uint4* __restrict__ uvp4,
    float* __restrict__ pv_num, float* __restrict__ pv_den)
{
  int b = blockIdx.x;
  if (b < RB_PV){ pv_body(b, be4, qE, qS, pv_num, pv_den); return; }
  b -= RB_PV;
  if (b < RB_ITEM){ item_body(b, be4, bu4, bp4, aS, aE, uS, uE, pS, pE, mat_vu, lam, out4, vp4); return; }
  b -= RB_ITEM;
  user_body(b, be4, bp4, vS, vE, ipi, mat_uv, eit4, uvp4);
}

// ======== finals (epilogues read bf16 tables) ========
__device__ __forceinline__ void item_final_body(int blk, ushort* As, ushort* Bs,
    const ushort* __restrict__ A0, const ushort* __restrict__ A1,
    const ushort* __restrict__ W,
    const float* __restrict__ ba, const float* __restrict__ bb,
    float* __restrict__ out)
{
  const int t = threadIdx.x;
  const int l = t & 63, wv = t >> 6;
  const int wr = (wv>>1)*64, wc = (wv&1)*64;
  const int row0 = blk*128;
  const int lr16 = t >> 3;
  const int slot = t & 7;
  f32x4 acc[4][4] = {};
  for (int s = 0; s < 4; ++s){
    if (s) __syncthreads();
    const int k0 = s*64;
    const ushort* srcA = (k0 < 128) ? (A0 + k0) : (A1 + (k0 - 128));
    #pragma unroll
    for (int i = 0; i < 4; ++i){
      int r = i*32 + lr16;
      int gr = row0 + r; if (gr >= N_NODE) gr = N_NODE-1;
      uint4 va = *(const uint4*)(srcA + (size_t)gr*128 + slot*8);
      *(uint4*)&As[r*64 + ((slot*8) ^ ((r&7)*8))] = va;
      uint4 vb = *(const uint4*)(W + r*256 + k0 + slot*8);
      *(uint4*)&Bs[r*64 + ((slot*8) ^ ((r&7)*8))] = vb;
    }
    __syncthreads();
    #pragma unroll
    for (int kk = 0; kk < 64; kk += 32){
      short8 af[4], bf[4];
      #pragma unroll
      for (int f = 0; f < 4; ++f){
        int ar = wr + f*16 + (l&15);
        af[f] = *(const short8*)&As[ar*64 + ((kk + (l>>4)*8) ^ ((ar&7)*8))];
        int bn = wc + f*16 + (l&15);
        bf[f] = *(const short8*)&Bs[bn*64 + ((kk + (l>>4)*8) ^ ((bn&7)*8))];
      }
      #pragma unroll
      for (int fi = 0; fi < 4; ++fi)
        #pragma unroll
        for (int fj = 0; fj < 4; ++fj)
          acc[fi][fj] = __builtin_amdgcn_mfma_f32_16x16x32_bf16(af[fi], bf[fj], acc[fi][fj], 0, 0, 0);
    }
  }
  const int g4 = (l>>4)*4;
  #pragma unroll
  for (int fi = 0; fi < 4; ++fi){
    #pragma unroll
    for (int r = 0; r < 4; ++r){
      int grow = row0 + wr + fi*16 + g4 + r;
      if (grow < N_NODE){
        #pragma unroll
        for (int fj = 0; fj < 4; ++fj){
          int col = wc + fj*16 + (l&15);
          float x = acc[fi][fj][r] + ba[col] + bb[col];
          unsigned pv2 = *(const unsigned*)&A1[(size_t)grow*128 + (col & ~1)];
          float v = (col & 1) ? bf_hi(pv2) : bf_lo(pv2);
          unsigned em2 = *(const unsigned*)&A0[(size_t)grow*128 + (col & ~1)];
          float em = (col & 1) ? bf_hi(em2) : bf_lo(em2);
          size_t o = (size_t)grow*128 + col;
          out[o] = em + sigf(x)*v + out[o];
        }
      }
    }
  }
}

__device__ __forceinline__ void user_final_body(int blk, ushort* As, ushort* Bs,
    const ushort* __restrict__ A0, const ushort* __restrict__ A1, const ushort* __restrict__ A2,
    const ushort* __restrict__ W,
    const float* __restrict__ bu,
    float* __restrict__ out)
{
  const int t = threadIdx.x;
  const int l = t & 63, wv = t >> 6;
  const int wr = (wv>>1)*64, wc = (wv&1)*64;
  const int row0 = blk*128;
  const int lr16 = t >> 3;
  const int slot = t & 7;
  f32x4 acc[4][4] = {};
  for (int s = 0; s < 6; ++s){
    if (s) __syncthreads();
    const int k0 = s*64;
    const ushort* base = (s < 2) ? A0 : ((s < 4) ? A1 : A2);
    const ushort* srcA = base + (s & 1)*64;
    #pragma unroll
    for (int i = 0; i < 4; ++i){
      int r = i*32 + lr16;
      int gr = row0 + r; if (gr >= N_USER) gr = N_USER-1;
      uint4 va = *(const uint4*)(srcA + (size_t)gr*128 + slot*8);
      *(uint4*)&As[r*64 + ((slot*8) ^ ((r&7)*8))] = va;
      uint4 vb = *(const uint4*)(W + r*384 + k0 + slot*8);
      *(uint4*)&Bs[r*64 + ((slot*8) ^ ((r&7)*8))] = vb;
    }
    __syncthreads();
    #pragma unroll
    for (int kk = 0; kk < 64; kk += 32){
      short8 af[4], bf[4];
      #pragma unroll
      for (int f = 0; f < 4; ++f){
        int ar = wr + f*16 + (l&15);
        af[f] = *(const short8*)&As[ar*64 + ((kk + (l>>4)*8) ^ ((ar&7)*8))];
        int bn = wc + f*16 + (l&15);
        bf[f] = *(const short8*)&Bs[bn*64 + ((kk + (l>>4)*8) ^ ((bn&7)*8))];
      }
      #pragma unroll
      for (int fi = 0; fi < 4; ++fi)
        #pragma unroll
        for (int fj = 0; fj < 4; ++fj)
          acc[fi][fj] = __builtin_amdgcn_mfma_f32_16x16x32_bf16(af[fi], bf[fj], acc[fi][fj], 0, 0, 0);
    }
  }
  const int g4 = (l>>4)*4;
  #pragma unroll
  for (int fi = 0; fi < 4; ++fi){
    #pragma unroll
    for (int r = 0; r < 4; ++r){
      int grow = row0 + wr + fi*16 + g4 + r;
      if (grow < N_USER){
        #pragma unroll
        for (int fj = 0; fj < 4; ++fj){
          int col = wc + fj*16 + (l&15);
          float g = sigf(acc[fi][fj][r] + bu[col]);
          unsigned e2 = *(const unsigned*)&A1[(size_t)grow*128 + (col & ~1)];
          float ei = (col & 1) ? bf_hi(e2) : bf_lo(e2);
          unsigned u2 = *(const unsigned*)&A0[(size_t)grow*128 + (col & ~1)];
          float uu = (col & 1) ? bf_hi(u2) : bf_lo(u2);
          size_t o = (size_t)grow*128 + col;
          out[o] = g*uu + (1.f - g)*ei;
        }
      }
    }
  }
}

__device__ __forceinline__ void price_final_body(int blk, float* A2,
    const float* __restrict__ pe, const float* __restrict__ num, const float* __restrict__ den,
    const float* __restrict__ mat_pv,
    const float* __restrict__ Wa, const float* __restrict__ ba,
    const float* __restrict__ Wb, const float* __restrict__ bb,
    float* __restrict__ out_price)
{
  int t = threadIdx.x;
  #pragma unroll
  for (int i = 0; i < 2; ++i){
    int flat = i*256 + t;
    int rl = flat >> 8; int k = flat & 255;
    int r = blk*2 + rl;
    float v;
    if (k < 128) v = pe[r*128 + k];
    else         v = num[r*128 + (k-128)] / (den[r] + 1e-8f) * mat_pv[r];
    A2[rl*256 + k] = v;
  }
  __syncthreads();
  int rl = t >> 7; int c = t & 127;
  int r = blk*2 + rl;
  float x = 0.f;
  #pragma unroll 4
  for (int k = 0; k < 256; ++k){
    float w = (k < 128) ? (Wa[c*256 + k] + Wb[c*128 + k]) : Wa[c*256 + k];
    x += A2[rl*256 + k]*w;
  }
  float g = sigf(x + ba[c] + bb[c]);
  out_price[r*128 + c] = pe[r*128 + c] + g*A2[rl*256 + 128 + c];
}

__global__ __launch_bounds__(256) void k_finals_all(
    const ushort* __restrict__ bemb, const ushort* __restrict__ vp_bf, const ushort* __restrict__ Wc,
    const float* __restrict__ b_aogi, const float* __restrict__ b_bgi1,
    float* __restrict__ out_item,
    const ushort* __restrict__ bue, const ushort* __restrict__ eitem_bf, const ushort* __restrict__ uvp_bf,
    const ushort* __restrict__ Wub, const float* __restrict__ b_user,
    float* __restrict__ out_user,
    const float* __restrict__ pe, const float* __restrict__ pv_num, const float* __restrict__ pv_den,
    const float* __restrict__ mat_pv,
    const float* __restrict__ W_aogp, const float* __restrict__ b_aogp,
    const float* __restrict__ W_bgp1, const float* __restrict__ b_bgp1,
    float* __restrict__ out_price)
{
  __shared__ __align__(16) ushort As[128*64];
  __shared__ __align__(16) ushort Bs[128*64];
  __shared__ float A2[512];
  int b = blockIdx.x;
  if (b < FB_ITEM){
    item_final_body(b, As, Bs, bemb, vp_bf, Wc, b_aogi, b_bgi1, out_item);
  } else if (b < FB_ITEM + FB_USER){
    user_final_body(b - FB_ITEM, As, Bs, bue, eitem_bf, uvp_bf, Wub, b_user, out_user);
  } else {
    price_final_body(b - FB_ITEM - FB_USER, A2, pe, pv_num, pv_den, mat_pv,
                     W_aogp, b_aogp, W_bgp1, b_bgp1, out_price);
  }
}

extern "C" void kernel_launch(void* const* d_in, const int* in_sizes, int n_in,
                              void* d_out, int out_size, void* d_ws, size_t ws_size,
                              hipStream_t stream){
  (void)in_sizes; (void)n_in; (void)out_size; (void)ws_size;
  const float* emb = (const float*)d_in[0];
  const float* pe  = (const float*)d_in[1];
  const float* ue  = (const float*)d_in[2];
  const int*   adj_r = (const int*)d_in[3];  const int* adj_c = (const int*)d_in[4];  const float* adj_v = (const float*)d_in[5];
  const int*   vp_r  = (const int*)d_in[6];  const int* vp_c  = (const int*)d_in[7];  const float* vp_v  = (const float*)d_in[8];
  const int*   vu_r  = (const int*)d_in[9];  const int* vu_c  = (const int*)d_in[10]; const float* vu_v  = (const float*)d_in[11];
  const int*   pv_r  = (const int*)d_in[12]; const int* pv_c  = (const int*)d_in[13]; const float* pv_v  = (const float*)d_in[14];
  const int*   uv_r  = (const int*)d_in[15]; const int* uv_c  = (const int*)d_in[16]; const float* uv_v  = (const float*)d_in[17];
  const int*   ipi   = (const int*)d_in[18];
  const float* mat_vu = (const float*)d_in[19];
  const float* mat_pv = (const float*)d_in[20];
  const float* mat_uv = (const float*)d_in[21];
  const float* W_aogi = (const float*)d_in[22]; const float* b_aogi = (const float*)d_in[23];
  const float* W_bgi1 = (const float*)d_in[24]; const float* b_bgi1 = (const float*)d_in[25];
  const float* W_aogp = (const float*)d_in[26]; const float* b_aogp = (const float*)d_in[27];
  const float* W_bgp1 = (const float*)d_in[28]; const float* b_bgp1 = (const float*)d_in[29];
  const float* W_user = (const float*)d_in[30]; const float* b_user = (const float*)d_in[31];
  const float* lam    = (const float*)d_in[32];

  float* out_item  = (float*)d_out;
  float* out_price = out_item + (size_t)N_NODE*EMB;
  float* out_user  = out_price + (size_t)N_PRICE*EMB;

  // edge staging lives in d_out (dead until k_rows_all/k_finals_all rewrite it)
  char* ob = (char*)d_out;
  const size_t SEGBIG = (size_t)256*8704*8;
  uint2* stgA = (uint2*)ob;
  uint2* stgU = (uint2*)(ob + SEGBIG);
  uint2* stgV = (uint2*)(ob + 2*SEGBIG);
  uint2* stgP = (uint2*)(ob + 3*SEGBIG);
  uint2* stgQ = (uint2*)(ob + 3*SEGBIG + (size_t)256*1536*8);

  char* w = (char*)d_ws;
  size_t off = 0;
  auto alloc = [&](size_t bytes)->char*{
    char* p = w + off;
    off = (off + bytes + 255) & ~(size_t)255;
    return p;
  };
  int* fill = (int*)alloc(FTOT*4);
  int* aS  = (int*)alloc((N_NODE+1)*4);
  int* uS  = (int*)alloc((N_NODE+1)*4);
  int* vS  = (int*)alloc((N_USER+1)*4);
  int* pS  = (int*)alloc((N_NODE+1)*4);
  int* qS  = (int*)alloc(101*4);
  ushort* Wc_item = (ushort*)alloc(128*256*2);
  ushort* Wu_bf   = (ushort*)alloc(128*384*2);
  char* region = alloc((size_t)62*1024*1024);
  unsigned* bemb = (unsigned*)region;
  unsigned* bue  = (unsigned*)(region + (size_t)N_NODE*EMB*2);
  unsigned* bpe  = (unsigned*)(region + (size_t)(N_NODE+N_USER)*EMB*2);
  unsigned* vp_bf = (unsigned*)(region + (size_t)(N_NODE+N_USER+N_PRICE)*EMB*2);
  int2*  adjE = (int2*)alloc(((size_t)E_VV+16)*8);
  int2*  vuE  = (int2*)alloc(((size_t)E_VU+16)*8);
  int2*  uvE  = (int2*)alloc(((size_t)E_UV+16)*8);
  int2*  vpE  = (int2*)alloc(((size_t)E_VP+16)*8);
  int2*  pvE  = (int2*)alloc(((size_t)E_VP+16)*8);
  unsigned* eitem_bf = (unsigned*)alloc((size_t)N_USER*64*4);
  unsigned* uvp_bf   = (unsigned*)alloc((size_t)N_USER*64*4);
  float* pv_num   = (float*)alloc((size_t)N_PRICE*EMB*4);
  float* pv_den   = (float*)alloc(N_PRICE*4);

  // 1) zero bucket fill counters
  hipMemsetAsync(fill, 0, FTOT*4, stream);

  // 2) front: bucket (stg in d_out) + weight prep
  k_front<<<FR_TOT,256,0,stream>>>(
      adj_r,adj_c,adj_v, vu_r,vu_c,vu_v, uv_r,uv_c,uv_v, vp_r,vp_c,vp_v, pv_r,pv_c,pv_v,
      fill, stgA, stgU, stgV, stgP, stgQ,
      W_aogi, W_bgi1, W_user, Wc_item, Wu_bf);

  // 3) CSR finalize + bf16 table cvt (cvt fills csr's idle wave slots)
  k_csr_all<<<CS_TOT,256,0,stream>>>(stgA, stgU, stgV, stgP, stgQ, fill,
      aS, uS, vS, pS, qS, adjE, vuE, uvE, vpE, pvE,
      (const float4*)emb, (const float4*)ue, (const float4*)pe,
      (uint2*)bemb, (uint2*)bue, (uint2*)bpe);

  // 4) all row-owned SpMMs (out_item overwrites dead staging in d_out)
  k_rows_all<<<RBT,256,0,stream>>>(
      (const uint4*)bemb, (const uint4*)bue, (const uint4*)bpe,
      aS, adjE, uS, vuE, pS, vpE, vS, uvE, qS, pvE,
      ipi, mat_vu, mat_uv, lam,
      (float4*)out_item, (uint4*)vp_bf, (uint4*)eitem_bf, (uint4*)uvp_bf,
      pv_num, pv_den);

  // 5) all finals
  k_finals_all<<<FBT,256,0,stream>>>(
      (const ushort*)bemb, (const ushort*)vp_bf, Wc_item, b_aogi, b_bgi1, out_item,
      (const ushort*)bue, (const ushort*)eitem_bf, (const ushort*)uvp_bf, Wu_bf, b_user, out_user,
      pe, pv_num, pv_den, mat_pv, W_aogp, b_aogp, W_bgp1, b_bgp1, out_price);
}